// Round 1
// baseline (3524.192 us; speedup 1.0000x reference)
//
#include <hip/hip_runtime.h>

#define D_MODEL 2048
#define GHD 512        // NUM_KV_GROUPS * HEAD_DIM
#define HD 128
#define NQH 16
#define NKVG 4
#define B_SZ 2
#define SEQ 2048
#define M_TOT (B_SZ * SEQ)   // 4096

// ---------------- fp32 tiled GEMM: C[M,N] = A[M,K] @ W[K,N] + bias ----------
// BM=BN=64, BK=16, 256 threads, 4x4 outputs/thread, float4 LDS reads.
__global__ __launch_bounds__(256) void gemm_bias_f32(
    const float* __restrict__ A, const float* __restrict__ W,
    const float* __restrict__ bias, float* __restrict__ C,
    int M, int N, int K)
{
    __shared__ float As[16][64];   // [k][m]
    __shared__ float Bs[16][64];   // [k][n]
    const int tid = threadIdx.x;
    const int tx = tid & 15, ty = tid >> 4;
    const int m0 = blockIdx.y << 6, n0 = blockIdx.x << 6;
    // A-tile load mapping: 64 rows x 16 cols, one float4 per thread
    const int lar = tid >> 2;            // 0..63
    const int lac = (tid & 3) << 2;      // 0,4,8,12
    // W-tile load mapping: 16 rows x 64 cols, one float4 per thread
    const int lbr = tid >> 4;            // 0..15
    const int lbc = (tid & 15) << 2;     // 0..60
    const float* Aptr = A + (size_t)(m0 + lar) * K + lac;
    const float* Wptr = W + (size_t)lbr * N + n0 + lbc;

    float acc[4][4] = {{0.f, 0.f, 0.f, 0.f}, {0.f, 0.f, 0.f, 0.f},
                       {0.f, 0.f, 0.f, 0.f}, {0.f, 0.f, 0.f, 0.f}};

    for (int k0 = 0; k0 < K; k0 += 16) {
        const float4 av = *(const float4*)(Aptr + k0);
        const float4 wv = *(const float4*)(Wptr + (size_t)k0 * N);
        __syncthreads();   // protect previous iteration's LDS reads
        As[lac + 0][lar] = av.x;
        As[lac + 1][lar] = av.y;
        As[lac + 2][lar] = av.z;
        As[lac + 3][lar] = av.w;
        *(float4*)&Bs[lbr][lbc] = wv;
        __syncthreads();
#pragma unroll
        for (int k = 0; k < 16; ++k) {
            const float4 a = *(const float4*)&As[k][ty << 2];
            const float4 b = *(const float4*)&Bs[k][tx << 2];
            acc[0][0] += a.x * b.x; acc[0][1] += a.x * b.y;
            acc[0][2] += a.x * b.z; acc[0][3] += a.x * b.w;
            acc[1][0] += a.y * b.x; acc[1][1] += a.y * b.y;
            acc[1][2] += a.y * b.z; acc[1][3] += a.y * b.w;
            acc[2][0] += a.z * b.x; acc[2][1] += a.z * b.y;
            acc[2][2] += a.z * b.z; acc[2][3] += a.z * b.w;
            acc[3][0] += a.w * b.x; acc[3][1] += a.w * b.y;
            acc[3][2] += a.w * b.z; acc[3][3] += a.w * b.w;
        }
    }
    const float4 bb = *(const float4*)&bias[n0 + (tx << 2)];
#pragma unroll
    for (int i = 0; i < 4; ++i) {
        float4 o;
        o.x = acc[i][0] + bb.x; o.y = acc[i][1] + bb.y;
        o.z = acc[i][2] + bb.z; o.w = acc[i][3] + bb.w;
        *(float4*)&C[(size_t)(m0 + (ty << 2) + i) * N + n0 + (tx << 2)] = o;
    }
}

// ---------------- fp32 flash attention (non-causal, GQA) --------------------
// One block = one (batch, head, 32-row Q chunk). KB=32 key tiles, online softmax.
__global__ __launch_bounds__(256) void flash_attn_f32(
    const float* __restrict__ Q, const float* __restrict__ Kp,
    const float* __restrict__ Vp, float* __restrict__ AO)
{
    __shared__ float Qs[32][128];  // swizzled by (row & 7) in float4 units
    __shared__ float Ks[32][128];  // swizzled by ((row>>2) & 7)
    __shared__ float Vs[32][128];  // linear
    __shared__ float Ps[32][33];   // [j][i], padded
    __shared__ float mrow[32], lrow[32], arow[32];

    const int tid = threadIdx.x;
    const int b = blockIdx.z, h = blockIdx.y, g = h >> 2;  // R = 4 q-heads/group
    const int q0 = blockIdx.x << 5;
    const float scale = 0.08838834764831845f;  // 1/sqrt(128)

    const float* Qb = Q + (size_t)(b * SEQ + q0) * D_MODEL + h * HD;
    const float* Kb = Kp + (size_t)b * SEQ * GHD + g * HD;
    const float* Vb = Vp + (size_t)b * SEQ * GHD + g * HD;

    // load + scale Q tile (32x128)
#pragma unroll
    for (int i = 0; i < 4; ++i) {
        const int idx = tid + (i << 8);      // 0..1023 float4 slots
        const int r = idx >> 5, u = idx & 31;
        float4 v = *(const float4*)(Qb + (size_t)r * D_MODEL + (u << 2));
        v.x *= scale; v.y *= scale; v.z *= scale; v.w *= scale;
        *(float4*)&Qs[r][(u ^ (r & 7)) << 2] = v;
    }
    if (tid < 32) { mrow[tid] = -1e30f; lrow[tid] = 0.f; }

    const int si = tid >> 3;             // score row 0..31
    const int sj0 = (tid & 7) << 2;      // score col group
    const int r_own = tid & 31;          // PV row ownership
    const int c0 = (tid >> 5) << 4;      // PV col offset (0 or 16) * ... 8 groups of 16
    float acc[16] = {0.f};

    for (int kt = 0; kt < SEQ; kt += 32) {
        // stage K,V tiles
#pragma unroll
        for (int i = 0; i < 4; ++i) {
            const int idx = tid + (i << 8);
            const int r = idx >> 5, u = idx & 31;
            *(float4*)&Ks[r][(u ^ ((r >> 2) & 7)) << 2] =
                *(const float4*)(Kb + (size_t)(kt + r) * GHD + (u << 2));
            *(float4*)&Vs[r][u << 2] =
                *(const float4*)(Vb + (size_t)(kt + r) * GHD + (u << 2));
        }
        __syncthreads();

        // scores: thread computes S[si][sj0..sj0+3]
        float s[4] = {0.f, 0.f, 0.f, 0.f};
#pragma unroll 8
        for (int k = 0; k < 128; k += 4) {
            const int u = k >> 2;
            const float4 q = *(const float4*)&Qs[si][(u ^ (si & 7)) << 2];
#pragma unroll
            for (int jj = 0; jj < 4; ++jj) {
                const int j = sj0 + jj;
                const float4 kv = *(const float4*)&Ks[j][(u ^ ((j >> 2) & 7)) << 2];
                s[jj] += q.x * kv.x + q.y * kv.y + q.z * kv.z + q.w * kv.w;
            }
        }
#pragma unroll
        for (int jj = 0; jj < 4; ++jj) Ps[sj0 + jj][si] = s[jj];
        __syncthreads();

        // online softmax (32 worker threads, one per query row)
        if (tid < 32) {
            const int i = tid;
            const float mold = mrow[i];
            float mnew = mold;
#pragma unroll 8
            for (int j = 0; j < 32; ++j) mnew = fmaxf(mnew, Ps[j][i]);
            const float a = __expf(mold - mnew);
            float sum = 0.f;
#pragma unroll 8
            for (int j = 0; j < 32; ++j) {
                const float p = __expf(Ps[j][i] - mnew);
                Ps[j][i] = p;
                sum += p;
            }
            lrow[i] = lrow[i] * a + sum;
            mrow[i] = mnew;
            arow[i] = a;
        }
        __syncthreads();

        // PV: thread owns row r_own, 16 contiguous cols at c0
        const float aa = arow[r_own];
#pragma unroll
        for (int cc = 0; cc < 16; ++cc) acc[cc] *= aa;
#pragma unroll 8
        for (int j = 0; j < 32; ++j) {
            const float p = Ps[j][r_own];
#pragma unroll
            for (int cv = 0; cv < 4; ++cv) {
                const float4 v = *(const float4*)&Vs[j][c0 + (cv << 2)];
                acc[cv * 4 + 0] += p * v.x;
                acc[cv * 4 + 1] += p * v.y;
                acc[cv * 4 + 2] += p * v.z;
                acc[cv * 4 + 3] += p * v.w;
            }
        }
        __syncthreads();   // protect Ks/Vs/Ps before next tile's staging
    }

    const float inv_l = 1.f / lrow[r_own];
    float* Ob = AO + (size_t)(b * SEQ + q0 + r_own) * D_MODEL + h * HD + c0;
#pragma unroll
    for (int cv = 0; cv < 4; ++cv) {
        float4 o;
        o.x = acc[cv * 4 + 0] * inv_l;
        o.y = acc[cv * 4 + 1] * inv_l;
        o.z = acc[cv * 4 + 2] * inv_l;
        o.w = acc[cv * 4 + 3] * inv_l;
        *(float4*)(Ob + (cv << 2)) = o;
    }
}

extern "C" void kernel_launch(void* const* d_in, const int* in_sizes, int n_in,
                              void* d_out, int out_size, void* d_ws, size_t ws_size,
                              hipStream_t stream)
{
    const float* x  = (const float*)d_in[0];
    const float* Wq = (const float*)d_in[1];
    const float* bq = (const float*)d_in[2];
    const float* Wk = (const float*)d_in[3];
    const float* bk = (const float*)d_in[4];
    const float* Wv = (const float*)d_in[5];
    const float* bv = (const float*)d_in[6];
    const float* Wo = (const float*)d_in[7];
    const float* bo = (const float*)d_in[8];
    float* out = (float*)d_out;

    // workspace layout (fp32): Q[4096x2048] K[4096x512] V[4096x512] AO[4096x2048]
    float* Qp = (float*)d_ws;
    float* Kp = Qp + (size_t)M_TOT * D_MODEL;
    float* Vp = Kp + (size_t)M_TOT * GHD;
    float* AO = Vp + (size_t)M_TOT * GHD;

    const dim3 blk(256);
    gemm_bias_f32<<<dim3(D_MODEL / 64, M_TOT / 64), blk, 0, stream>>>(
        x, Wq, bq, Qp, M_TOT, D_MODEL, D_MODEL);
    gemm_bias_f32<<<dim3(GHD / 64, M_TOT / 64), blk, 0, stream>>>(
        x, Wk, bk, Kp, M_TOT, GHD, D_MODEL);
    gemm_bias_f32<<<dim3(GHD / 64, M_TOT / 64), blk, 0, stream>>>(
        x, Wv, bv, Vp, M_TOT, GHD, D_MODEL);
    flash_attn_f32<<<dim3(SEQ / 32, NQH, B_SZ), blk, 0, stream>>>(Qp, Kp, Vp, AO);
    gemm_bias_f32<<<dim3(D_MODEL / 64, M_TOT / 64), blk, 0, stream>>>(
        AO, Wo, bo, out, M_TOT, D_MODEL, D_MODEL);
}

// Round 2
// 1777.333 us; speedup vs baseline: 1.9829x; 1.9829x over previous
//
#include <hip/hip_runtime.h>

#define D_MODEL 2048
#define GHD 512        // NUM_KV_GROUPS * HEAD_DIM
#define HD 128
#define NQH 16
#define NKVG 4
#define B_SZ 2
#define SEQ 2048
#define M_TOT (B_SZ * SEQ)   // 4096

typedef _Float16 f16;
typedef _Float16 f16x8 __attribute__((ext_vector_type(8)));
typedef float f32x4 __attribute__((ext_vector_type(4)));

// ---------------- fp32 tiled GEMM: C[M,N] = A[M,K] @ W[K,N] + bias ----------
__global__ __launch_bounds__(256) void gemm_bias_f32(
    const float* __restrict__ A, const float* __restrict__ W,
    const float* __restrict__ bias, float* __restrict__ C,
    int M, int N, int K)
{
    __shared__ float As[16][64];   // [k][m]
    __shared__ float Bs[16][64];   // [k][n]
    const int tid = threadIdx.x;
    const int tx = tid & 15, ty = tid >> 4;
    const int m0 = blockIdx.y << 6, n0 = blockIdx.x << 6;
    const int lar = tid >> 2;
    const int lac = (tid & 3) << 2;
    const int lbr = tid >> 4;
    const int lbc = (tid & 15) << 2;
    const float* Aptr = A + (size_t)(m0 + lar) * K + lac;
    const float* Wptr = W + (size_t)lbr * N + n0 + lbc;

    float acc[4][4] = {{0.f, 0.f, 0.f, 0.f}, {0.f, 0.f, 0.f, 0.f},
                       {0.f, 0.f, 0.f, 0.f}, {0.f, 0.f, 0.f, 0.f}};

    for (int k0 = 0; k0 < K; k0 += 16) {
        const float4 av = *(const float4*)(Aptr + k0);
        const float4 wv = *(const float4*)(Wptr + (size_t)k0 * N);
        __syncthreads();
        As[lac + 0][lar] = av.x;
        As[lac + 1][lar] = av.y;
        As[lac + 2][lar] = av.z;
        As[lac + 3][lar] = av.w;
        *(float4*)&Bs[lbr][lbc] = wv;
        __syncthreads();
#pragma unroll
        for (int k = 0; k < 16; ++k) {
            const float4 a = *(const float4*)&As[k][ty << 2];
            const float4 b = *(const float4*)&Bs[k][tx << 2];
            acc[0][0] += a.x * b.x; acc[0][1] += a.x * b.y;
            acc[0][2] += a.x * b.z; acc[0][3] += a.x * b.w;
            acc[1][0] += a.y * b.x; acc[1][1] += a.y * b.y;
            acc[1][2] += a.y * b.z; acc[1][3] += a.y * b.w;
            acc[2][0] += a.z * b.x; acc[2][1] += a.z * b.y;
            acc[2][2] += a.z * b.z; acc[2][3] += a.z * b.w;
            acc[3][0] += a.w * b.x; acc[3][1] += a.w * b.y;
            acc[3][2] += a.w * b.z; acc[3][3] += a.w * b.w;
        }
    }
    const float4 bb = *(const float4*)&bias[n0 + (tx << 2)];
#pragma unroll
    for (int i = 0; i < 4; ++i) {
        float4 o;
        o.x = acc[i][0] + bb.x; o.y = acc[i][1] + bb.y;
        o.z = acc[i][2] + bb.z; o.w = acc[i][3] + bb.w;
        *(float4*)&C[(size_t)(m0 + (ty << 2) + i) * N + n0 + (tx << 2)] = o;
    }
}

// ---------------- fp16-MFMA flash attention (non-causal, GQA) ---------------
// 4 waves/block; wave w owns q-rows [w*16, w*16+16). KV tile = 64 rows.
// mfma_f32_16x16x32_f16. A-frag: row=lane&15, k=(lane>>4)*8+j.
// B-frag: col=lane&15, k=(lane>>4)*8+j (i.e. loads like A from [N][K] storage).
// C/D: col=lane&15, row=(lane>>4)*4+reg.
__global__ __launch_bounds__(256) void flash_attn_mfma(
    const float* __restrict__ Q, const float* __restrict__ Kp,
    const float* __restrict__ Vp, float* __restrict__ AO)
{
    // XOR-swizzled LDS (16B units, unit ^= row&7) to kill stride-128B same-bank reads
    __shared__ f16 Ks[64 * 128];      // K tile, row-major [kb][d], swizzled
    __shared__ f16 Vt[128 * 64];      // V tile transposed [d][kb], swizzled
    __shared__ f16 Pl[4][16 * 64];    // per-wave P [qrow][kb], swizzled

    const int tid = threadIdx.x;
    const int w = tid >> 6, l = tid & 63;
    const int l15 = l & 15, lq = l >> 4;        // lq = 0..3
    const int b = blockIdx.z, h = blockIdx.y, g = h >> 2;
    const int q0 = blockIdx.x << 6;
    const float scale = 0.08838834764831845f;   // 1/sqrt(128)

    const float* Qb = Q + (size_t)(b * SEQ + q0) * D_MODEL + h * HD;
    const float* Kb = Kp + (size_t)b * SEQ * GHD + g * HD;
    const float* Vb = Vp + (size_t)b * SEQ * GHD + g * HD;

    // ---- Q fragments to registers (scale folded in), once per block
    f16x8 aq[4];
    {
        const float* qrow = Qb + (size_t)(w * 16 + l15) * D_MODEL;
#pragma unroll
        for (int c = 0; c < 4; ++c) {
            const int d0 = c * 32 + lq * 8;
            const float4 v0 = *(const float4*)(qrow + d0);
            const float4 v1 = *(const float4*)(qrow + d0 + 4);
            f16x8 a;
            a[0] = (f16)(v0.x * scale); a[1] = (f16)(v0.y * scale);
            a[2] = (f16)(v0.z * scale); a[3] = (f16)(v0.w * scale);
            a[4] = (f16)(v1.x * scale); a[5] = (f16)(v1.y * scale);
            a[6] = (f16)(v1.z * scale); a[7] = (f16)(v1.w * scale);
            aq[c] = a;
        }
    }

    f32x4 acc_o[8];
#pragma unroll
    for (int i = 0; i < 8; ++i) acc_o[i] = (f32x4){0.f, 0.f, 0.f, 0.f};
    float m_r[4] = {-1e30f, -1e30f, -1e30f, -1e30f};
    float l_r[4] = {0.f, 0.f, 0.f, 0.f};

    for (int kt = 0; kt < SEQ; kt += 64) {
        // ---- stage K tile (fp32 -> fp16, swizzled), 64 rows x 16 units
#pragma unroll
        for (int i = 0; i < 4; ++i) {
            const int s = tid + (i << 8);
            const int row = s >> 4, u = s & 15;
            const float* src = Kb + (size_t)(kt + row) * GHD + u * 8;
            const float4 v0 = *(const float4*)src;
            const float4 v1 = *(const float4*)(src + 4);
            f16x8 hv;
            hv[0] = (f16)v0.x; hv[1] = (f16)v0.y; hv[2] = (f16)v0.z; hv[3] = (f16)v0.w;
            hv[4] = (f16)v1.x; hv[5] = (f16)v1.y; hv[6] = (f16)v1.z; hv[7] = (f16)v1.w;
            *(f16x8*)&Ks[row * 128 + ((u ^ (row & 7)) << 3)] = hv;
        }
        // ---- stage V transposed (fp32 -> fp16, swizzled)
#pragma unroll
        for (int i = 0; i < 8; ++i) {
            const int c = tid + (i << 8);
            const int kb = c >> 5, dc = c & 31;
            const float4 v = *(const float4*)(Vb + (size_t)(kt + kb) * GHD + dc * 4);
            const float hv[4] = {v.x, v.y, v.z, v.w};
            const int u = kb >> 3;
#pragma unroll
            for (int e = 0; e < 4; ++e) {
                const int rd = dc * 4 + e;
                Vt[rd * 64 + ((u ^ (rd & 7)) << 3) + (kb & 7)] = (f16)hv[e];
            }
        }
        __syncthreads();

        // ---- QK^T: wave computes S[16][64] as 4 col-blocks
        f32x4 sa[4];
#pragma unroll
        for (int cb = 0; cb < 4; ++cb) {
            sa[cb] = (f32x4){0.f, 0.f, 0.f, 0.f};
#pragma unroll
            for (int c = 0; c < 4; ++c) {
                const int rk = cb * 16 + l15;
                const int u = c * 4 + lq;
                const f16x8 bk = *(const f16x8*)&Ks[rk * 128 + ((u ^ (rk & 7)) << 3)];
                sa[cb] = __builtin_amdgcn_mfma_f32_16x16x32_f16(aq[c], bk, sa[cb], 0, 0, 0);
            }
        }

        // ---- online softmax, wave-parallel (rows live in 16-lane groups)
#pragma unroll
        for (int reg = 0; reg < 4; ++reg) {
            float mx = fmaxf(fmaxf(sa[0][reg], sa[1][reg]),
                             fmaxf(sa[2][reg], sa[3][reg]));
            mx = fmaxf(mx, __shfl_xor(mx, 1));
            mx = fmaxf(mx, __shfl_xor(mx, 2));
            mx = fmaxf(mx, __shfl_xor(mx, 4));
            mx = fmaxf(mx, __shfl_xor(mx, 8));
            const float mnew = fmaxf(m_r[reg], mx);
            const float alpha = __expf(m_r[reg] - mnew);
            m_r[reg] = mnew;
            const int r = lq * 4 + reg;
            float sum = 0.f;
#pragma unroll
            for (int cb = 0; cb < 4; ++cb) {
                const float p = __expf(sa[cb][reg] - mnew);
                sum += p;
                const int col = cb * 16 + l15;
                const int u = col >> 3;
                Pl[w][r * 64 + ((u ^ (r & 7)) << 3) + (col & 7)] = (f16)p;
            }
            sum += __shfl_xor(sum, 1);
            sum += __shfl_xor(sum, 2);
            sum += __shfl_xor(sum, 4);
            sum += __shfl_xor(sum, 8);
            l_r[reg] = l_r[reg] * alpha + sum;
#pragma unroll
            for (int db = 0; db < 8; ++db) acc_o[db][reg] *= alpha;
        }

        // ---- PV: O[16][128] += P[16][64] @ V[64][128]
#pragma unroll
        for (int kc = 0; kc < 2; ++kc) {
            const int rp = l15;
            const int up = kc * 4 + lq;
            const f16x8 pa = *(const f16x8*)&Pl[w][rp * 64 + ((up ^ (rp & 7)) << 3)];
#pragma unroll
            for (int db = 0; db < 8; ++db) {
                const int rv = db * 16 + l15;
                const int uv = kc * 4 + lq;
                const f16x8 bv = *(const f16x8*)&Vt[rv * 64 + ((uv ^ (rv & 7)) << 3)];
                acc_o[db] = __builtin_amdgcn_mfma_f32_16x16x32_f16(pa, bv, acc_o[db], 0, 0, 0);
            }
        }
        __syncthreads();   // protect Ks/Vt before next staging
    }

    // ---- epilogue: divide by l, write fp32 AO in C-layout positions
    float inv_l[4];
#pragma unroll
    for (int reg = 0; reg < 4; ++reg) inv_l[reg] = 1.f / l_r[reg];
    float* Ob = AO + (size_t)(b * SEQ + q0 + w * 16) * D_MODEL + h * HD;
#pragma unroll
    for (int db = 0; db < 8; ++db) {
#pragma unroll
        for (int reg = 0; reg < 4; ++reg) {
            Ob[(size_t)(lq * 4 + reg) * D_MODEL + db * 16 + l15] =
                acc_o[db][reg] * inv_l[reg];
        }
    }
}

extern "C" void kernel_launch(void* const* d_in, const int* in_sizes, int n_in,
                              void* d_out, int out_size, void* d_ws, size_t ws_size,
                              hipStream_t stream)
{
    const float* x  = (const float*)d_in[0];
    const float* Wq = (const float*)d_in[1];
    const float* bq = (const float*)d_in[2];
    const float* Wk = (const float*)d_in[3];
    const float* bk = (const float*)d_in[4];
    const float* Wv = (const float*)d_in[5];
    const float* bv = (const float*)d_in[6];
    const float* Wo = (const float*)d_in[7];
    const float* bo = (const float*)d_in[8];
    float* out = (float*)d_out;

    float* Qp = (float*)d_ws;
    float* Kp = Qp + (size_t)M_TOT * D_MODEL;
    float* Vp = Kp + (size_t)M_TOT * GHD;
    float* AO = Vp + (size_t)M_TOT * GHD;

    const dim3 blk(256);
    gemm_bias_f32<<<dim3(D_MODEL / 64, M_TOT / 64), blk, 0, stream>>>(
        x, Wq, bq, Qp, M_TOT, D_MODEL, D_MODEL);
    gemm_bias_f32<<<dim3(GHD / 64, M_TOT / 64), blk, 0, stream>>>(
        x, Wk, bk, Kp, M_TOT, GHD, D_MODEL);
    gemm_bias_f32<<<dim3(GHD / 64, M_TOT / 64), blk, 0, stream>>>(
        x, Wv, bv, Vp, M_TOT, GHD, D_MODEL);
    flash_attn_mfma<<<dim3(SEQ / 64, NQH, B_SZ), blk, 0, stream>>>(Qp, Kp, Vp, AO);
    gemm_bias_f32<<<dim3(D_MODEL / 64, M_TOT / 64), blk, 0, stream>>>(
        AO, Wo, bo, out, M_TOT, D_MODEL, D_MODEL);
}

// Round 3
// 671.857 us; speedup vs baseline: 5.2454x; 2.6454x over previous
//
#include <hip/hip_runtime.h>

#define D_MODEL 2048
#define GHD 512        // NUM_KV_GROUPS * HEAD_DIM
#define HD 128
#define NQH 16
#define NKVG 4
#define B_SZ 2
#define SEQ 2048
#define M_TOT (B_SZ * SEQ)   // 4096

typedef _Float16 f16;
typedef _Float16 f16x4 __attribute__((ext_vector_type(4)));
typedef _Float16 f16x8 __attribute__((ext_vector_type(8)));
typedef float f32x4 __attribute__((ext_vector_type(4)));

// ---------------------------------------------------------------------------
// Transpose + hi/lo fp16 split: W[K][N] fp32 -> Th/Tl[(row_off+n)][K] f16
// ---------------------------------------------------------------------------
__global__ __launch_bounds__(256) void transpose_split(
    const float* __restrict__ W, f16* __restrict__ Th, f16* __restrict__ Tl,
    int K, int N, int row_off)
{
    __shared__ float Ls[32][33];
    const int t = threadIdx.x;
    const int n0 = blockIdx.x << 5, k0 = blockIdx.y << 5;
    {
        const int kr = t >> 3, nq = (t & 7) << 2;
        const float4 v = *(const float4*)&W[(size_t)(k0 + kr) * N + n0 + nq];
        Ls[kr][nq + 0] = v.x; Ls[kr][nq + 1] = v.y;
        Ls[kr][nq + 2] = v.z; Ls[kr][nq + 3] = v.w;
    }
    __syncthreads();
    const int nr = t >> 3, kq = (t & 7) << 2;
    f16x4 hv, lv;
#pragma unroll
    for (int e = 0; e < 4; ++e) {
        const float a = Ls[kq + e][nr];
        const f16 h = (f16)a;
        hv[e] = h;
        lv[e] = (f16)(a - (float)h);
    }
    const size_t off = (size_t)(row_off + n0 + nr) * K + k0 + kq;
    *(f16x4*)&Th[off] = hv;
    *(f16x4*)&Tl[off] = lv;
}

// ---------------------------------------------------------------------------
// Split-precision MFMA GEMM: C[M][N] = A[M][K](fp32) @ B(W^T hi/lo f16) + bias
// 3-term split: Ah*Bh + Al*Bh + Ah*Bl. BM=128, BK=32, 256 threads (4 waves).
// BN=128: wave grid 2x2 (wave tile 64x64); BN=64: 4x1 (wave tile 32x64).
// LDS rows padded to 40 f16 (80 B) -> fragment reads are 2-way (free).
// ---------------------------------------------------------------------------
template<int BN, bool OUT32>
__global__ __launch_bounds__(256) void gemm_split(
    const float* __restrict__ A,
    const f16* __restrict__ BTh, const f16* __restrict__ BTl,
    const float* __restrict__ bias0, const float* __restrict__ bias1,
    void* __restrict__ C0v, void* __restrict__ C1v,
    int Nsplit, int ld0, int ld1, int K)
{
    constexpr int WN = BN / 64;            // waves along n: 2 or 1
    constexpr int WM = 4 / WN;             // waves along m: 2 or 4
    constexpr int WI = 128 / (WM * 16);    // m-frags per wave: 4 or 2
    constexpr int LDK = 40;                // padded row length (f16)
    constexpr int NB = (BN * 4) / 256;     // B 16B-units per thread per array

    __shared__ f16 Ah[128 * LDK], Al[128 * LDK];
    __shared__ f16 Bh[BN * LDK],  Bl[BN * LDK];

    const int tid = threadIdx.x;
    const int l = tid & 63, w = tid >> 6;
    const int l15 = l & 15, lq = l >> 4;
    const int wr = w / WN, wc = w % WN;
    const int m0 = blockIdx.y << 7;
    const int n0 = blockIdx.x * BN;

    f32x4 acc[WI][4];
#pragma unroll
    for (int i = 0; i < WI; ++i)
#pragma unroll
        for (int j = 0; j < 4; ++j) acc[i][j] = (f32x4){0.f, 0.f, 0.f, 0.f};

    const int amr = tid >> 3, akq = (tid & 7) << 2;   // A: m-row, k-quad
    const int bnr = tid >> 2, buk = (tid & 3) << 3;   // B: n-row, k-oct
    const float* Ap  = A   + (size_t)(m0 + amr) * K + akq;
    const f16*  Bhp  = BTh + (size_t)(n0 + bnr) * K + buk;
    const f16*  Blp  = BTl + (size_t)(n0 + bnr) * K + buk;

    for (int k0 = 0; k0 < K; k0 += 32) {
        float4 av[4];
#pragma unroll
        for (int it = 0; it < 4; ++it)
            av[it] = *(const float4*)(Ap + (size_t)(it * 32) * K + k0);
        f16x8 bhv[NB], blv[NB];
#pragma unroll
        for (int it = 0; it < NB; ++it) {
            bhv[it] = *(const f16x8*)(Bhp + (size_t)(it * 64) * K + k0);
            blv[it] = *(const f16x8*)(Blp + (size_t)(it * 64) * K + k0);
        }
        __syncthreads();   // protect previous iteration's fragment reads
#pragma unroll
        for (int it = 0; it < 4; ++it) {
            f16x4 hv, lv;
            const float a0 = av[it].x, a1 = av[it].y, a2 = av[it].z, a3 = av[it].w;
            hv[0] = (f16)a0; lv[0] = (f16)(a0 - (float)hv[0]);
            hv[1] = (f16)a1; lv[1] = (f16)(a1 - (float)hv[1]);
            hv[2] = (f16)a2; lv[2] = (f16)(a2 - (float)hv[2]);
            hv[3] = (f16)a3; lv[3] = (f16)(a3 - (float)hv[3]);
            const int base = (amr + it * 32) * LDK + akq;
            *(f16x4*)&Ah[base] = hv;
            *(f16x4*)&Al[base] = lv;
        }
#pragma unroll
        for (int it = 0; it < NB; ++it) {
            const int base = (bnr + it * 64) * LDK + buk;
            *(f16x8*)&Bh[base] = bhv[it];
            *(f16x8*)&Bl[base] = blv[it];
        }
        __syncthreads();

        f16x8 af[WI][2];
#pragma unroll
        for (int i = 0; i < WI; ++i) {
            const int row = wr * (WI * 16) + i * 16 + l15;
            af[i][0] = *(const f16x8*)&Ah[row * LDK + lq * 8];
            af[i][1] = *(const f16x8*)&Al[row * LDK + lq * 8];
        }
#pragma unroll
        for (int j = 0; j < 4; ++j) {
            const int bn = wc * 64 + j * 16 + l15;
            const f16x8 bfh = *(const f16x8*)&Bh[bn * LDK + lq * 8];
            const f16x8 bfl = *(const f16x8*)&Bl[bn * LDK + lq * 8];
#pragma unroll
            for (int i = 0; i < WI; ++i)
                acc[i][j] = __builtin_amdgcn_mfma_f32_16x16x32_f16(af[i][0], bfh, acc[i][j], 0, 0, 0);
#pragma unroll
            for (int i = 0; i < WI; ++i)
                acc[i][j] = __builtin_amdgcn_mfma_f32_16x16x32_f16(af[i][1], bfh, acc[i][j], 0, 0, 0);
#pragma unroll
            for (int i = 0; i < WI; ++i)
                acc[i][j] = __builtin_amdgcn_mfma_f32_16x16x32_f16(af[i][0], bfl, acc[i][j], 0, 0, 0);
        }
    }

    // epilogue: C-layout col=l15, row=lq*4+reg
#pragma unroll
    for (int j = 0; j < 4; ++j) {
        const int ng = n0 + wc * 64 + j * 16 + l15;
        const bool first = ng < Nsplit;
        const float bvf = first ? bias0[ng] : bias1[ng - Nsplit];
        const int nc = first ? ng : ng - Nsplit;
        const int ldc = first ? ld0 : ld1;
#pragma unroll
        for (int i = 0; i < WI; ++i) {
            const int mg = m0 + wr * (WI * 16) + i * 16 + lq * 4;
#pragma unroll
            for (int r = 0; r < 4; ++r) {
                const float v = acc[i][j][r] + bvf;
                if (OUT32)
                    ((float*)(first ? C0v : C1v))[(size_t)(mg + r) * ldc + nc] = v;
                else
                    ((f16*)(first ? C0v : C1v))[(size_t)(mg + r) * ldc + nc] = (f16)v;
            }
        }
    }
}

// ---------------------------------------------------------------------------
// fp16-MFMA flash attention (non-causal, GQA), f16 inputs, fp32 AO out.
// 4 waves/block; wave w owns q-rows [w*16, w*16+16). KV tile = 64 rows.
// ---------------------------------------------------------------------------
__global__ __launch_bounds__(256) void flash_attn_mfma(
    const f16* __restrict__ Q, const f16* __restrict__ Kp,
    const f16* __restrict__ Vp, float* __restrict__ AO)
{
    __shared__ f16 Ks[64 * 128];      // K tile, row-major [kb][d], swizzled
    __shared__ f16 Vt[128 * 64];      // V tile transposed [d][kb], swizzled
    __shared__ f16 Pl[4][16 * 64];    // per-wave P [qrow][kb], swizzled

    const int tid = threadIdx.x;
    const int w = tid >> 6, l = tid & 63;
    const int l15 = l & 15, lq = l >> 4;
    const int b = blockIdx.z, h = blockIdx.y, g = h >> 2;
    const int q0 = blockIdx.x << 6;
    const float scale = 0.08838834764831845f;   // 1/sqrt(128)

    const f16* Qb = Q + (size_t)(b * SEQ + q0) * D_MODEL + h * HD;
    const f16* Kb = Kp + (size_t)b * SEQ * GHD + g * HD;
    const f16* Vb = Vp + (size_t)b * SEQ * GHD + g * HD;

    // Q fragments (f16 direct)
    f16x8 aq[4];
    {
        const f16* qrow = Qb + (size_t)(w * 16 + l15) * D_MODEL;
#pragma unroll
        for (int c = 0; c < 4; ++c)
            aq[c] = *(const f16x8*)(qrow + c * 32 + lq * 8);
    }

    f32x4 acc_o[8];
#pragma unroll
    for (int i = 0; i < 8; ++i) acc_o[i] = (f32x4){0.f, 0.f, 0.f, 0.f};
    float m_r[4] = {-1e30f, -1e30f, -1e30f, -1e30f};
    float l_r[4] = {0.f, 0.f, 0.f, 0.f};

    for (int kt = 0; kt < SEQ; kt += 64) {
        // stage K tile (f16 copy, swizzled)
#pragma unroll
        for (int i = 0; i < 4; ++i) {
            const int s = tid + (i << 8);
            const int row = s >> 4, u = s & 15;
            *(f16x8*)&Ks[row * 128 + ((u ^ (row & 7)) << 3)] =
                *(const f16x8*)(Kb + (size_t)(kt + row) * GHD + u * 8);
        }
        // stage V transposed (swizzled)
#pragma unroll
        for (int i = 0; i < 4; ++i) {
            const int s = tid + (i << 8);
            const int kb = s >> 4, du = s & 15;
            const f16x8 v = *(const f16x8*)(Vb + (size_t)(kt + kb) * GHD + du * 8);
            const int u = kb >> 3;
#pragma unroll
            for (int e = 0; e < 8; ++e) {
                const int rd = du * 8 + e;
                Vt[rd * 64 + ((u ^ (rd & 7)) << 3) + (kb & 7)] = v[e];
            }
        }
        __syncthreads();

        // QK^T
        f32x4 sa[4];
#pragma unroll
        for (int cb = 0; cb < 4; ++cb) {
            sa[cb] = (f32x4){0.f, 0.f, 0.f, 0.f};
#pragma unroll
            for (int c = 0; c < 4; ++c) {
                const int rk = cb * 16 + l15;
                const f16x8 bk = *(const f16x8*)&Ks[rk * 128 + (((c * 4 + lq) ^ (rk & 7)) << 3)];
                sa[cb] = __builtin_amdgcn_mfma_f32_16x16x32_f16(aq[c], bk, sa[cb], 0, 0, 0);
            }
            sa[cb] *= scale;
        }

        // online softmax (wave-parallel)
#pragma unroll
        for (int reg = 0; reg < 4; ++reg) {
            float mx = fmaxf(fmaxf(sa[0][reg], sa[1][reg]),
                             fmaxf(sa[2][reg], sa[3][reg]));
            mx = fmaxf(mx, __shfl_xor(mx, 1));
            mx = fmaxf(mx, __shfl_xor(mx, 2));
            mx = fmaxf(mx, __shfl_xor(mx, 4));
            mx = fmaxf(mx, __shfl_xor(mx, 8));
            const float mnew = fmaxf(m_r[reg], mx);
            const float alpha = __expf(m_r[reg] - mnew);
            m_r[reg] = mnew;
            const int r = lq * 4 + reg;
            float sum = 0.f;
#pragma unroll
            for (int cb = 0; cb < 4; ++cb) {
                const float p = __expf(sa[cb][reg] - mnew);
                sum += p;
                const int col = cb * 16 + l15;
                Pl[w][r * 64 + (((col >> 3) ^ (r & 7)) << 3) + (col & 7)] = (f16)p;
            }
            sum += __shfl_xor(sum, 1);
            sum += __shfl_xor(sum, 2);
            sum += __shfl_xor(sum, 4);
            sum += __shfl_xor(sum, 8);
            l_r[reg] = l_r[reg] * alpha + sum;
#pragma unroll
            for (int db = 0; db < 8; ++db) acc_o[db][reg] *= alpha;
        }

        // PV
#pragma unroll
        for (int kc = 0; kc < 2; ++kc) {
            const int rp = l15;
            const int up = kc * 4 + lq;
            const f16x8 pa = *(const f16x8*)&Pl[w][rp * 64 + ((up ^ (rp & 7)) << 3)];
#pragma unroll
            for (int db = 0; db < 8; ++db) {
                const int rv = db * 16 + l15;
                const int uv = kc * 4 + lq;
                const f16x8 bv = *(const f16x8*)&Vt[rv * 64 + ((uv ^ (rv & 7)) << 3)];
                acc_o[db] = __builtin_amdgcn_mfma_f32_16x16x32_f16(pa, bv, acc_o[db], 0, 0, 0);
            }
        }
        __syncthreads();
    }

    float inv_l[4];
#pragma unroll
    for (int reg = 0; reg < 4; ++reg) inv_l[reg] = 1.f / l_r[reg];
    float* Ob = AO + (size_t)(b * SEQ + q0 + w * 16) * D_MODEL + h * HD;
#pragma unroll
    for (int db = 0; db < 8; ++db) {
#pragma unroll
        for (int reg = 0; reg < 4; ++reg) {
            Ob[(size_t)(lq * 4 + reg) * D_MODEL + db * 16 + l15] =
                acc_o[db][reg] * inv_l[reg];
        }
    }
}

extern "C" void kernel_launch(void* const* d_in, const int* in_sizes, int n_in,
                              void* d_out, int out_size, void* d_ws, size_t ws_size,
                              hipStream_t stream)
{
    const float* x  = (const float*)d_in[0];
    const float* Wq = (const float*)d_in[1];
    const float* bq = (const float*)d_in[2];
    const float* Wk = (const float*)d_in[3];
    const float* bk = (const float*)d_in[4];
    const float* Wv = (const float*)d_in[5];
    const float* bv = (const float*)d_in[6];
    const float* Wo = (const float*)d_in[7];
    const float* bo = (const float*)d_in[8];
    float* out = (float*)d_out;

    // workspace (f16 offsets). AO (fp32, 33.55 MB) aliases WqT+WkvT+pad,
    // which are dead once the Q/KV GEMMs complete. Total: 75.5 MB.
    f16* base   = (f16*)d_ws;
    f16* WqT_h  = base;                         // 4.19M f16
    f16* WqT_l  = base + 4194304;
    f16* WkvT_h = base + 8388608;               // 2.10M f16 (K rows 0..511, V rows 512..1023)
    f16* WkvT_l = base + 10485760;
    // pad: f16 [12582912, 16777216) — tail of AO
    float* AO   = (float*)d_ws;                 // 8.39M fp32 = f16 [0, 16777216)
    f16* WoT_h  = base + 16777216;
    f16* WoT_l  = base + 20971520;
    f16* Qp     = base + 25165824;              // 8.39M f16
    f16* Kp     = base + 33554432;              // 2.10M
    f16* Vp     = base + 35651584;              // 2.10M  (end: 37748736 f16 = 75.5 MB)

    const dim3 blk(256);
    // 1) transpose + split weights
    transpose_split<<<dim3(64, 64), blk, 0, stream>>>(Wq, WqT_h, WqT_l, 2048, 2048, 0);
    transpose_split<<<dim3(16, 64), blk, 0, stream>>>(Wk, WkvT_h, WkvT_l, 2048, 512, 0);
    transpose_split<<<dim3(16, 64), blk, 0, stream>>>(Wv, WkvT_h, WkvT_l, 2048, 512, 512);
    transpose_split<<<dim3(64, 64), blk, 0, stream>>>(Wo, WoT_h, WoT_l, 2048, 2048, 0);
    // 2) projections (split-precision fp16 MFMA)
    gemm_split<128, false><<<dim3(16, 32), blk, 0, stream>>>(
        x, WqT_h, WqT_l, bq, bq, Qp, Qp, 2048, 2048, 2048, 2048);
    gemm_split<64, false><<<dim3(16, 32), blk, 0, stream>>>(
        x, WkvT_h, WkvT_l, bk, bv, Kp, Vp, 512, 512, 512, 2048);
    // 3) attention
    flash_attn_mfma<<<dim3(SEQ / 64, NQH, B_SZ), blk, 0, stream>>>(Qp, Kp, Vp, AO);
    // 4) output projection (fp32 out)
    gemm_split<128, true><<<dim3(16, 32), blk, 0, stream>>>(
        AO, WoT_h, WoT_l, bo, bo, out, out, 2048, 2048, 2048, 2048);
}

// Round 4
// 517.401 us; speedup vs baseline: 6.8113x; 1.2985x over previous
//
#include <hip/hip_runtime.h>

#define D_MODEL 2048
#define GHD 512        // NUM_KV_GROUPS * HEAD_DIM
#define HD 128
#define NQH 16
#define B_SZ 2
#define SEQ 2048
#define M_TOT (B_SZ * SEQ)   // 4096

typedef _Float16 f16;
typedef _Float16 f16x4 __attribute__((ext_vector_type(4)));
typedef _Float16 f16x8 __attribute__((ext_vector_type(8)));
typedef float f32x4 __attribute__((ext_vector_type(4)));

typedef const __attribute__((address_space(1))) void gvoid;
typedef __attribute__((address_space(3))) void lvoid;
typedef __attribute__((address_space(3))) f16 lf16;

// hardware transpose read: lane l, elem j <- lds[(l&15) + j*16 + (l>>4)*64]
// relative to (per-lane addr = base + l*8B) + compile-time offset.
template<int OFF>
__device__ __forceinline__ f16x4 tr16(unsigned a) {
    f16x4 d;
    asm volatile("ds_read_b64_tr_b16 %0, %1 offset:%2"
                 : "=v"(d) : "v"(a), "i"(OFF));
    return d;
}

// ---------------------------------------------------------------------------
// x (fp32) -> hi/lo f16 split, elementwise
// ---------------------------------------------------------------------------
__global__ __launch_bounds__(256) void split_f32(
    const float* __restrict__ X, f16* __restrict__ Xh, f16* __restrict__ Xl)
{
    const size_t i = ((size_t)blockIdx.x * 256 + threadIdx.x) * 8;
    const float4 v0 = *(const float4*)(X + i);
    const float4 v1 = *(const float4*)(X + i + 4);
    const float a[8] = {v0.x, v0.y, v0.z, v0.w, v1.x, v1.y, v1.z, v1.w};
    f16x8 h, lo;
#pragma unroll
    for (int e = 0; e < 8; ++e) {
        h[e] = (f16)a[e];
        lo[e] = (f16)(a[e] - (float)h[e]);
    }
    *(f16x8*)(Xh + i) = h;
    *(f16x8*)(Xl + i) = lo;
}

// ---------------------------------------------------------------------------
// Transpose + hi/lo fp16 split: W[K][N] fp32 -> Th/Tl[(row_off+n)][K] f16
// ---------------------------------------------------------------------------
__global__ __launch_bounds__(256) void transpose_split(
    const float* __restrict__ W, f16* __restrict__ Th, f16* __restrict__ Tl,
    int K, int N, int row_off)
{
    __shared__ float Ls[32][33];
    const int t = threadIdx.x;
    const int n0 = blockIdx.x << 5, k0 = blockIdx.y << 5;
    {
        const int kr = t >> 3, nq = (t & 7) << 2;
        const float4 v = *(const float4*)&W[(size_t)(k0 + kr) * N + n0 + nq];
        Ls[kr][nq + 0] = v.x; Ls[kr][nq + 1] = v.y;
        Ls[kr][nq + 2] = v.z; Ls[kr][nq + 3] = v.w;
    }
    __syncthreads();
    const int nr = t >> 3, kq = (t & 7) << 2;
    f16x4 hv, lv;
#pragma unroll
    for (int e = 0; e < 4; ++e) {
        const float a = Ls[kq + e][nr];
        const f16 h = (f16)a;
        hv[e] = h;
        lv[e] = (f16)(a - (float)h);
    }
    const size_t off = (size_t)(row_off + n0 + nr) * K + k0 + kq;
    *(f16x4*)&Th[off] = hv;
    *(f16x4*)&Tl[off] = lv;
}

// ---------------------------------------------------------------------------
// Split-precision MFMA GEMM with pre-split f16 A and B (W^T) inputs.
// C = (Ah+Al) @ (Bh+Bl)^T + bias, 3 terms: AhBh + AlBh + AhBl. BM=128, BK=32.
// ---------------------------------------------------------------------------
template<int BN, bool OUT32>
__global__ __launch_bounds__(256) void gemm_split(
    const f16* __restrict__ Agh, const f16* __restrict__ Agl,
    const f16* __restrict__ BTh, const f16* __restrict__ BTl,
    const float* __restrict__ bias0, const float* __restrict__ bias1,
    void* __restrict__ C0v, void* __restrict__ C1v,
    int Nsplit, int ld0, int ld1, int K, float outscale)
{
    constexpr int WN = BN / 64;            // waves along n
    constexpr int WM = 4 / WN;             // waves along m
    constexpr int WI = 128 / (WM * 16);    // m-frags per wave
    constexpr int LDK = 40;                // padded row (f16)
    constexpr int NB = (BN * 4) / 256;     // B chunks per thread per array

    __shared__ f16 Ah[128 * LDK], Al[128 * LDK];
    __shared__ f16 Bh[BN * LDK],  Bl[BN * LDK];

    const int tid = threadIdx.x;
    const int l = tid & 63, w = tid >> 6;
    const int l15 = l & 15, lq = l >> 4;
    const int wr = w / WN, wc = w % WN;
    const int m0 = blockIdx.y << 7;
    const int n0 = blockIdx.x * BN;

    f32x4 acc[WI][4];
#pragma unroll
    for (int i = 0; i < WI; ++i)
#pragma unroll
        for (int j = 0; j < 4; ++j) acc[i][j] = (f32x4){0.f, 0.f, 0.f, 0.f};

    const int ar  = tid >> 2;              // 0..63 (rows ar, ar+64)
    const int auk = (tid & 3) << 3;        // 0,8,16,24
    const f16* Ahp = Agh + (size_t)(m0 + ar) * K + auk;
    const f16* Alp = Agl + (size_t)(m0 + ar) * K + auk;
    const int bnr = tid >> 2, buk = (tid & 3) << 3;
    const f16* Bhp = BTh + (size_t)(n0 + bnr) * K + buk;
    const f16* Blp = BTl + (size_t)(n0 + bnr) * K + buk;

    for (int k0 = 0; k0 < K; k0 += 32) {
        const f16x8 a0h = *(const f16x8*)(Ahp + k0);
        const f16x8 a1h = *(const f16x8*)(Ahp + (size_t)64 * K + k0);
        const f16x8 a0l = *(const f16x8*)(Alp + k0);
        const f16x8 a1l = *(const f16x8*)(Alp + (size_t)64 * K + k0);
        f16x8 bhv[NB], blv[NB];
#pragma unroll
        for (int it = 0; it < NB; ++it) {
            bhv[it] = *(const f16x8*)(Bhp + (size_t)(it * 64) * K + k0);
            blv[it] = *(const f16x8*)(Blp + (size_t)(it * 64) * K + k0);
        }
        __syncthreads();   // protect previous iteration's fragment reads
        *(f16x8*)&Ah[ar * LDK + auk] = a0h;
        *(f16x8*)&Ah[(ar + 64) * LDK + auk] = a1h;
        *(f16x8*)&Al[ar * LDK + auk] = a0l;
        *(f16x8*)&Al[(ar + 64) * LDK + auk] = a1l;
#pragma unroll
        for (int it = 0; it < NB; ++it) {
            *(f16x8*)&Bh[(bnr + it * 64) * LDK + buk] = bhv[it];
            *(f16x8*)&Bl[(bnr + it * 64) * LDK + buk] = blv[it];
        }
        __syncthreads();

        f16x8 afh[WI], afl[WI];
#pragma unroll
        for (int i = 0; i < WI; ++i) {
            const int row = wr * (WI * 16) + i * 16 + l15;
            afh[i] = *(const f16x8*)&Ah[row * LDK + lq * 8];
            afl[i] = *(const f16x8*)&Al[row * LDK + lq * 8];
        }
#pragma unroll
        for (int j = 0; j < 4; ++j) {
            const int bn = wc * 64 + j * 16 + l15;
            const f16x8 bfh = *(const f16x8*)&Bh[bn * LDK + lq * 8];
            const f16x8 bfl = *(const f16x8*)&Bl[bn * LDK + lq * 8];
#pragma unroll
            for (int i = 0; i < WI; ++i)
                acc[i][j] = __builtin_amdgcn_mfma_f32_16x16x32_f16(afh[i], bfh, acc[i][j], 0, 0, 0);
#pragma unroll
            for (int i = 0; i < WI; ++i)
                acc[i][j] = __builtin_amdgcn_mfma_f32_16x16x32_f16(afl[i], bfh, acc[i][j], 0, 0, 0);
#pragma unroll
            for (int i = 0; i < WI; ++i)
                acc[i][j] = __builtin_amdgcn_mfma_f32_16x16x32_f16(afh[i], bfl, acc[i][j], 0, 0, 0);
        }
    }

#pragma unroll
    for (int j = 0; j < 4; ++j) {
        const int ng = n0 + wc * 64 + j * 16 + l15;
        const bool first = ng < Nsplit;
        const float bvf = first ? bias0[ng] : bias1[ng - Nsplit];
        const int nc = first ? ng : ng - Nsplit;
        const int ldc = first ? ld0 : ld1;
#pragma unroll
        for (int i = 0; i < WI; ++i) {
            const int mg = m0 + wr * (WI * 16) + i * 16 + lq * 4;
#pragma unroll
            for (int r = 0; r < 4; ++r) {
                const float v = (acc[i][j][r] + bvf) * outscale;
                if (OUT32)
                    ((float*)(first ? C0v : C1v))[(size_t)(mg + r) * ldc + nc] = v;
                else
                    ((f16*)(first ? C0v : C1v))[(size_t)(mg + r) * ldc + nc] = (f16)v;
            }
        }
    }
}

// ---------------------------------------------------------------------------
// PV step: 8 db-blocks of O += P @ V using hardware-transpose V reads.
// V subtile slot order: slot = dsub*16 + kc*8 + jh*4 + lq; [4][16] row-major.
// tr offset for (db,KC,jh) = (db*16 + KC*8 + jh*4)*128 bytes.
// ---------------------------------------------------------------------------
#define SHUF8(x, y) __builtin_shufflevector(x, y, 0, 1, 2, 3, 4, 5, 6, 7)

template<int KC>
__device__ __forceinline__ void pv_step(const f16* __restrict__ PlW, unsigned vta,
                                        int l15, int lq, f32x4 (&acc)[8])
{
    const f16x8 pa = *(const f16x8*)&PlW[l15 * 64 + (((KC * 4 + lq) ^ (l15 & 7)) << 3)];
    {
        f16x4 a0 = tr16<0 * 2048 + KC * 1024 + 0>(vta);
        f16x4 b0 = tr16<0 * 2048 + KC * 1024 + 512>(vta);
        f16x4 a1 = tr16<1 * 2048 + KC * 1024 + 0>(vta);
        f16x4 b1 = tr16<1 * 2048 + KC * 1024 + 512>(vta);
        f16x4 a2 = tr16<2 * 2048 + KC * 1024 + 0>(vta);
        f16x4 b2 = tr16<2 * 2048 + KC * 1024 + 512>(vta);
        f16x4 a3 = tr16<3 * 2048 + KC * 1024 + 0>(vta);
        f16x4 b3 = tr16<3 * 2048 + KC * 1024 + 512>(vta);
        asm volatile("s_waitcnt lgkmcnt(0)" ::: "memory");
        __builtin_amdgcn_sched_barrier(0);
        acc[0] = __builtin_amdgcn_mfma_f32_16x16x32_f16(pa, SHUF8(a0, b0), acc[0], 0, 0, 0);
        acc[1] = __builtin_amdgcn_mfma_f32_16x16x32_f16(pa, SHUF8(a1, b1), acc[1], 0, 0, 0);
        acc[2] = __builtin_amdgcn_mfma_f32_16x16x32_f16(pa, SHUF8(a2, b2), acc[2], 0, 0, 0);
        acc[3] = __builtin_amdgcn_mfma_f32_16x16x32_f16(pa, SHUF8(a3, b3), acc[3], 0, 0, 0);
    }
    {
        f16x4 a4 = tr16<4 * 2048 + KC * 1024 + 0>(vta);
        f16x4 b4 = tr16<4 * 2048 + KC * 1024 + 512>(vta);
        f16x4 a5 = tr16<5 * 2048 + KC * 1024 + 0>(vta);
        f16x4 b5 = tr16<5 * 2048 + KC * 1024 + 512>(vta);
        f16x4 a6 = tr16<6 * 2048 + KC * 1024 + 0>(vta);
        f16x4 b6 = tr16<6 * 2048 + KC * 1024 + 512>(vta);
        f16x4 a7 = tr16<7 * 2048 + KC * 1024 + 0>(vta);
        f16x4 b7 = tr16<7 * 2048 + KC * 1024 + 512>(vta);
        asm volatile("s_waitcnt lgkmcnt(0)" ::: "memory");
        __builtin_amdgcn_sched_barrier(0);
        acc[4] = __builtin_amdgcn_mfma_f32_16x16x32_f16(pa, SHUF8(a4, b4), acc[4], 0, 0, 0);
        acc[5] = __builtin_amdgcn_mfma_f32_16x16x32_f16(pa, SHUF8(a5, b5), acc[5], 0, 0, 0);
        acc[6] = __builtin_amdgcn_mfma_f32_16x16x32_f16(pa, SHUF8(a6, b6), acc[6], 0, 0, 0);
        acc[7] = __builtin_amdgcn_mfma_f32_16x16x32_f16(pa, SHUF8(a7, b7), acc[7], 0, 0, 0);
    }
}

// ---------------------------------------------------------------------------
// fp16-MFMA flash attention, async staging, tr-read V, hi/lo f16 output.
// 4 waves/block; wave w owns q-rows [w*16, w*16+16). KV tile = 64 rows.
// Scale (1/sqrt(128)) is pre-folded into Q by the Q-projection GEMM.
// ---------------------------------------------------------------------------
__global__ __launch_bounds__(256) void flash_attn_mfma(
    const f16* __restrict__ Q, const f16* __restrict__ Kp,
    const f16* __restrict__ Vp, f16* __restrict__ AOh, f16* __restrict__ AOl)
{
    __shared__ f16 Ks[64 * 128];      // [row][u_lin], u_lin = u_g ^ (row&7)
    __shared__ f16 Vt[64 * 128];      // subtiled for tr16 (see pv_step)
    __shared__ f16 Pl[4][16 * 64];    // per-wave P, swizzled

    const int tid = threadIdx.x;
    const int w = tid >> 6, l = tid & 63;
    const int l15 = l & 15, lq = l >> 4;
    const int b = blockIdx.z, h = blockIdx.y, g = h >> 2;
    const int q0 = blockIdx.x << 6;

    const f16* Qb = Q + (size_t)(b * SEQ + q0) * D_MODEL + h * HD;
    const f16* Kb = Kp + (size_t)b * SEQ * GHD + g * HD;
    const f16* Vb = Vp + (size_t)b * SEQ * GHD + g * HD;

    // Q fragments (scale already folded in)
    f16x8 aq[4];
    {
        const f16* qrow = Qb + (size_t)(w * 16 + l15) * D_MODEL;
#pragma unroll
        for (int c = 0; c < 4; ++c)
            aq[c] = *(const f16x8*)(qrow + c * 32 + lq * 8);
    }

    // precompute async-staging source/dest (advance source by kt*GHD each tile)
    lf16* Ks3 = (lf16*)Ks;
    lf16* Vt3 = (lf16*)Vt;
    const f16* ksrc[4]; lf16* kdst[4];
    const f16* vsrc[4]; lf16* vdst[4];
#pragma unroll
    for (int i = 0; i < 4; ++i) {
        const int s = tid + (i << 8);          // 16B-chunk index 0..1023
        {   // K: row-major, source chunk permuted by row&7 (read uses same XOR)
            const int row = s >> 4, ul = s & 15;
            ksrc[i] = Kb + (size_t)row * GHD + ((ul ^ (row & 7)) << 3);
            kdst[i] = Ks3 + s * 8;
        }
        {   // V: subtiled dest; invert chunk index -> (kv, d)
            const int dbit = s & 1, kvlo = (s >> 1) & 3, vlq = (s >> 3) & 3;
            const int jh = (s >> 5) & 1, kc = (s >> 6) & 1, dsub = s >> 7;
            const int kv = (kc << 5) | (vlq << 3) | (jh << 2) | kvlo;
            vsrc[i] = Vb + (size_t)kv * GHD + ((dsub << 4) | (dbit << 3));
            vdst[i] = Vt3 + s * 8;
        }
    }
    const unsigned vta = (unsigned)(size_t)(Vt3 + l * 4);   // lane*8 bytes
    const f16* PlW = &Pl[w][0];

    f32x4 acc_o[8];
#pragma unroll
    for (int i = 0; i < 8; ++i) acc_o[i] = (f32x4){0.f, 0.f, 0.f, 0.f};
    float m_r[4] = {-1e30f, -1e30f, -1e30f, -1e30f};
    float l_r[4] = {0.f, 0.f, 0.f, 0.f};

    for (int kt = 0; kt < SEQ; kt += 64) {
        const size_t koff = (size_t)kt * GHD;
#pragma unroll
        for (int i = 0; i < 4; ++i)
            __builtin_amdgcn_global_load_lds((gvoid*)(ksrc[i] + koff),
                                             (lvoid*)kdst[i], 16, 0, 0);
#pragma unroll
        for (int i = 0; i < 4; ++i)
            __builtin_amdgcn_global_load_lds((gvoid*)(vsrc[i] + koff),
                                             (lvoid*)vdst[i], 16, 0, 0);
        __syncthreads();

        // QK^T
        f32x4 sa[4];
#pragma unroll
        for (int cb = 0; cb < 4; ++cb) {
            sa[cb] = (f32x4){0.f, 0.f, 0.f, 0.f};
#pragma unroll
            for (int c = 0; c < 4; ++c) {
                const int rk = cb * 16 + l15;
                const f16x8 bk = *(const f16x8*)&Ks[rk * 128 + (((c * 4 + lq) ^ (rk & 7)) << 3)];
                sa[cb] = __builtin_amdgcn_mfma_f32_16x16x32_f16(aq[c], bk, sa[cb], 0, 0, 0);
            }
        }

        // online softmax (wave-parallel, rows in 16-lane groups)
#pragma unroll
        for (int reg = 0; reg < 4; ++reg) {
            float mx = fmaxf(fmaxf(sa[0][reg], sa[1][reg]),
                             fmaxf(sa[2][reg], sa[3][reg]));
            mx = fmaxf(mx, __shfl_xor(mx, 1));
            mx = fmaxf(mx, __shfl_xor(mx, 2));
            mx = fmaxf(mx, __shfl_xor(mx, 4));
            mx = fmaxf(mx, __shfl_xor(mx, 8));
            const float mnew = fmaxf(m_r[reg], mx);
            const float alpha = __expf(m_r[reg] - mnew);
            m_r[reg] = mnew;
            const int r = lq * 4 + reg;
            float sum = 0.f;
#pragma unroll
            for (int cb = 0; cb < 4; ++cb) {
                const float p = __expf(sa[cb][reg] - mnew);
                sum += p;
                const int col = cb * 16 + l15;
                Pl[w][r * 64 + (((col >> 3) ^ (r & 7)) << 3) + (col & 7)] = (f16)p;
            }
            sum += __shfl_xor(sum, 1);
            sum += __shfl_xor(sum, 2);
            sum += __shfl_xor(sum, 4);
            sum += __shfl_xor(sum, 8);
            l_r[reg] = l_r[reg] * alpha + sum;
#pragma unroll
            for (int db = 0; db < 8; ++db) acc_o[db][reg] *= alpha;
        }

        // PV via hardware transpose reads
        pv_step<0>(PlW, vta, l15, lq, acc_o);
        pv_step<1>(PlW, vta, l15, lq, acc_o);
        __syncthreads();   // protect Ks/Vt before next tile's staging
    }

    // epilogue: divide by l, write hi/lo f16 AO
    float inv_l[4];
#pragma unroll
    for (int reg = 0; reg < 4; ++reg) inv_l[reg] = 1.f / l_r[reg];
    const size_t obase = (size_t)(b * SEQ + q0 + w * 16) * D_MODEL + h * HD;
#pragma unroll
    for (int db = 0; db < 8; ++db) {
#pragma unroll
        for (int reg = 0; reg < 4; ++reg) {
            const size_t off = obase + (size_t)(lq * 4 + reg) * D_MODEL + db * 16 + l15;
            const float v = acc_o[db][reg] * inv_l[reg];
            const f16 hh = (f16)v;
            AOh[off] = hh;
            AOl[off] = (f16)(v - (float)hh);
        }
    }
}

extern "C" void kernel_launch(void* const* d_in, const int* in_sizes, int n_in,
                              void* d_out, int out_size, void* d_ws, size_t ws_size,
                              hipStream_t stream)
{
    const float* x  = (const float*)d_in[0];
    const float* Wq = (const float*)d_in[1];
    const float* bq = (const float*)d_in[2];
    const float* Wk = (const float*)d_in[3];
    const float* bk = (const float*)d_in[4];
    const float* Wv = (const float*)d_in[5];
    const float* bv = (const float*)d_in[6];
    const float* Wo = (const float*)d_in[7];
    const float* bo = (const float*)d_in[8];
    float* out = (float*)d_out;

    // workspace (f16 units), total 41,943,040 f16 = 83.9 MB (== round-1 proven).
    // AOh/AOl alias xh/xl (x dead after QKV GEMMs); Wo^T reuses Wq^T slot.
    f16* base   = (f16*)d_ws;
    f16* xh     = base;                 // 8388608
    f16* xl     = base + 8388608;       // 8388608
    f16* WkvT_h = base + 16777216;      // 2097152
    f16* WkvT_l = base + 18874368;      // 2097152
    f16* WqoT_h = base + 20971520;      // 4194304
    f16* WqoT_l = base + 25165824;      // 4194304
    f16* Qp     = base + 29360128;      // 8388608
    f16* Kp     = base + 37748736;      // 2097152
    f16* Vp     = base + 39845888;      // 2097152 -> end 41943040
    f16* AOh    = xh;
    f16* AOl    = xl;

    const dim3 blk(256);
    const float qscale = 0.08838834764831845f;   // 1/sqrt(128)

    split_f32<<<dim3(M_TOT * D_MODEL / 8 / 256), blk, 0, stream>>>(x, xh, xl);
    transpose_split<<<dim3(64, 64), blk, 0, stream>>>(Wq, WqoT_h, WqoT_l, 2048, 2048, 0);
    transpose_split<<<dim3(16, 64), blk, 0, stream>>>(Wk, WkvT_h, WkvT_l, 2048, 512, 0);
    transpose_split<<<dim3(16, 64), blk, 0, stream>>>(Wv, WkvT_h, WkvT_l, 2048, 512, 512);

    gemm_split<128, false><<<dim3(16, 32), blk, 0, stream>>>(
        xh, xl, WqoT_h, WqoT_l, bq, bq, Qp, Qp, 2048, 2048, 2048, 2048, qscale);
    gemm_split<64, false><<<dim3(16, 32), blk, 0, stream>>>(
        xh, xl, WkvT_h, WkvT_l, bk, bv, Kp, Vp, 512, 512, 512, 2048, 1.0f);

    // Wo^T into the (now dead) Wq^T slot, before attention overwrites xh/xl
    transpose_split<<<dim3(64, 64), blk, 0, stream>>>(Wo, WqoT_h, WqoT_l, 2048, 2048, 0);

    flash_attn_mfma<<<dim3(SEQ / 64, NQH, B_SZ), blk, 0, stream>>>(Qp, Kp, Vp, AOh, AOl);

    gemm_split<128, true><<<dim3(16, 32), blk, 0, stream>>>(
        AOh, AOl, WqoT_h, WqoT_l, bo, bo, out, out, 2048, 2048, 2048, 2048, 1.0f);
}

// Round 5
// 487.787 us; speedup vs baseline: 7.2249x; 1.0607x over previous
//
#include <hip/hip_runtime.h>

#define D_MODEL 2048
#define GHD 512        // NUM_KV_GROUPS * HEAD_DIM
#define HD 128
#define NQH 16
#define B_SZ 2
#define SEQ 2048
#define M_TOT (B_SZ * SEQ)   // 4096

typedef _Float16 f16;
typedef _Float16 f16x4 __attribute__((ext_vector_type(4)));
typedef _Float16 f16x8 __attribute__((ext_vector_type(8)));
typedef float f32x4 __attribute__((ext_vector_type(4)));

typedef const __attribute__((address_space(1))) void gvoid;
typedef __attribute__((address_space(3))) void lvoid;
typedef __attribute__((address_space(3))) f16 lf16;

// raw barrier (no vmcnt(0) drain, unlike __syncthreads) with compiler fences
#define BAR() do { asm volatile("" ::: "memory"); \
                   __builtin_amdgcn_s_barrier();  \
                   asm volatile("" ::: "memory"); } while (0)
#define WAIT_VM8() asm volatile("s_waitcnt vmcnt(8)" ::: "memory")
#define WAIT_VM0() asm volatile("s_waitcnt vmcnt(0)" ::: "memory")

// hardware transpose read: lane l, elem j <- lds[(l&15) + j*16 + (l>>4)*64]
template<int OFF>
__device__ __forceinline__ f16x4 tr16(unsigned a) {
    f16x4 d;
    asm volatile("ds_read_b64_tr_b16 %0, %1 offset:%2"
                 : "=v"(d) : "v"(a), "i"(OFF));
    return d;
}

// ---------------------------------------------------------------------------
// x (fp32) -> hi/lo f16 split, elementwise
// ---------------------------------------------------------------------------
__global__ __launch_bounds__(256) void split_f32(
    const float* __restrict__ X, f16* __restrict__ Xh, f16* __restrict__ Xl)
{
    const size_t i = ((size_t)blockIdx.x * 256 + threadIdx.x) * 8;
    const float4 v0 = *(const float4*)(X + i);
    const float4 v1 = *(const float4*)(X + i + 4);
    const float a[8] = {v0.x, v0.y, v0.z, v0.w, v1.x, v1.y, v1.z, v1.w};
    f16x8 h, lo;
#pragma unroll
    for (int e = 0; e < 8; ++e) {
        h[e] = (f16)a[e];
        lo[e] = (f16)(a[e] - (float)h[e]);
    }
    *(f16x8*)(Xh + i) = h;
    *(f16x8*)(Xl + i) = lo;
}

// ---------------------------------------------------------------------------
// Transpose + hi/lo fp16 split: W[K][N] fp32 -> Th/Tl[(row_off+n)][K] f16
// ---------------------------------------------------------------------------
__global__ __launch_bounds__(256) void transpose_split(
    const float* __restrict__ W, f16* __restrict__ Th, f16* __restrict__ Tl,
    int K, int N, int row_off)
{
    __shared__ float Ls[32][33];
    const int t = threadIdx.x;
    const int n0 = blockIdx.x << 5, k0 = blockIdx.y << 5;
    {
        const int kr = t >> 3, nq = (t & 7) << 2;
        const float4 v = *(const float4*)&W[(size_t)(k0 + kr) * N + n0 + nq];
        Ls[kr][nq + 0] = v.x; Ls[kr][nq + 1] = v.y;
        Ls[kr][nq + 2] = v.z; Ls[kr][nq + 3] = v.w;
    }
    __syncthreads();
    const int nr = t >> 3, kq = (t & 7) << 2;
    f16x4 hv, lv;
#pragma unroll
    for (int e = 0; e < 4; ++e) {
        const float a = Ls[kq + e][nr];
        const f16 h = (f16)a;
        hv[e] = h;
        lv[e] = (f16)(a - (float)h);
    }
    const size_t off = (size_t)(row_off + n0 + nr) * K + k0 + kq;
    *(f16x4*)&Th[off] = hv;
    *(f16x4*)&Tl[off] = lv;
}

// ---------------------------------------------------------------------------
// Split-precision MFMA GEMM, pre-split f16 A and B (W^T) inputs.
// 3 terms: AhBh + AlBh + AhBl. BM=128, BK=32, 256 threads (4 waves).
// Next-k0 global loads issued AFTER the LDS-write sync so they fly under
// the MFMA phase (T14 issue-early); last-iter over-read stays inside d_ws.
// ---------------------------------------------------------------------------
template<int BN, bool OUT32>
__global__ __launch_bounds__(256) void gemm_split(
    const f16* __restrict__ Agh, const f16* __restrict__ Agl,
    const f16* __restrict__ BTh, const f16* __restrict__ BTl,
    const float* __restrict__ bias0, const float* __restrict__ bias1,
    void* __restrict__ C0v, void* __restrict__ C1v,
    int Nsplit, int ld0, int ld1, int K, float outscale)
{
    constexpr int WN = BN / 64;
    constexpr int WM = 4 / WN;
    constexpr int WI = 128 / (WM * 16);
    constexpr int LDK = 40;
    constexpr int NB = (BN * 4) / 256;

    __shared__ f16 Ah[128 * LDK], Al[128 * LDK];
    __shared__ f16 Bh[BN * LDK],  Bl[BN * LDK];

    const int tid = threadIdx.x;
    const int l = tid & 63, w = tid >> 6;
    const int l15 = l & 15, lq = l >> 4;
    const int wr = w / WN, wc = w % WN;
    const int m0 = blockIdx.y << 7;
    const int n0 = blockIdx.x * BN;

    f32x4 acc[WI][4];
#pragma unroll
    for (int i = 0; i < WI; ++i)
#pragma unroll
        for (int j = 0; j < 4; ++j) acc[i][j] = (f32x4){0.f, 0.f, 0.f, 0.f};

    const int ar  = tid >> 2;
    const int auk = (tid & 3) << 3;
    const f16* Ahp = Agh + (size_t)(m0 + ar) * K + auk;
    const f16* Alp = Agl + (size_t)(m0 + ar) * K + auk;
    const int bnr = tid >> 2, buk = (tid & 3) << 3;
    const f16* Bhp = BTh + (size_t)(n0 + bnr) * K + buk;
    const f16* Blp = BTl + (size_t)(n0 + bnr) * K + buk;

    // prologue loads for k0 = 0
    f16x8 a0h = *(const f16x8*)(Ahp);
    f16x8 a1h = *(const f16x8*)(Ahp + (size_t)64 * K);
    f16x8 a0l = *(const f16x8*)(Alp);
    f16x8 a1l = *(const f16x8*)(Alp + (size_t)64 * K);
    f16x8 bhv[NB], blv[NB];
#pragma unroll
    for (int it = 0; it < NB; ++it) {
        bhv[it] = *(const f16x8*)(Bhp + (size_t)(it * 64) * K);
        blv[it] = *(const f16x8*)(Blp + (size_t)(it * 64) * K);
    }

    for (int k0 = 0; k0 < K; k0 += 32) {
        __syncthreads();   // previous iteration's fragment reads done
        *(f16x8*)&Ah[ar * LDK + auk] = a0h;
        *(f16x8*)&Ah[(ar + 64) * LDK + auk] = a1h;
        *(f16x8*)&Al[ar * LDK + auk] = a0l;
        *(f16x8*)&Al[(ar + 64) * LDK + auk] = a1l;
#pragma unroll
        for (int it = 0; it < NB; ++it) {
            *(f16x8*)&Bh[(bnr + it * 64) * LDK + buk] = bhv[it];
            *(f16x8*)&Bl[(bnr + it * 64) * LDK + buk] = blv[it];
        }
        __syncthreads();

        // prefetch next k0 (flies under the MFMA phase; harmless in-ws
        // over-read on the last iteration)
        const int kn = k0 + 32;
        a0h = *(const f16x8*)(Ahp + kn);
        a1h = *(const f16x8*)(Ahp + (size_t)64 * K + kn);
        a0l = *(const f16x8*)(Alp + kn);
        a1l = *(const f16x8*)(Alp + (size_t)64 * K + kn);
#pragma unroll
        for (int it = 0; it < NB; ++it) {
            bhv[it] = *(const f16x8*)(Bhp + (size_t)(it * 64) * K + kn);
            blv[it] = *(const f16x8*)(Blp + (size_t)(it * 64) * K + kn);
        }

        f16x8 afh[WI], afl[WI];
#pragma unroll
        for (int i = 0; i < WI; ++i) {
            const int row = wr * (WI * 16) + i * 16 + l15;
            afh[i] = *(const f16x8*)&Ah[row * LDK + lq * 8];
            afl[i] = *(const f16x8*)&Al[row * LDK + lq * 8];
        }
#pragma unroll
        for (int j = 0; j < 4; ++j) {
            const int bn = wc * 64 + j * 16 + l15;
            const f16x8 bfh = *(const f16x8*)&Bh[bn * LDK + lq * 8];
            const f16x8 bfl = *(const f16x8*)&Bl[bn * LDK + lq * 8];
#pragma unroll
            for (int i = 0; i < WI; ++i)
                acc[i][j] = __builtin_amdgcn_mfma_f32_16x16x32_f16(afh[i], bfh, acc[i][j], 0, 0, 0);
#pragma unroll
            for (int i = 0; i < WI; ++i)
                acc[i][j] = __builtin_amdgcn_mfma_f32_16x16x32_f16(afl[i], bfh, acc[i][j], 0, 0, 0);
#pragma unroll
            for (int i = 0; i < WI; ++i)
                acc[i][j] = __builtin_amdgcn_mfma_f32_16x16x32_f16(afh[i], bfl, acc[i][j], 0, 0, 0);
        }
    }

#pragma unroll
    for (int j = 0; j < 4; ++j) {
        const int ng = n0 + wc * 64 + j * 16 + l15;
        const bool first = ng < Nsplit;
        const float bvf = first ? bias0[ng] : bias1[ng - Nsplit];
        const int nc = first ? ng : ng - Nsplit;
        const int ldc = first ? ld0 : ld1;
#pragma unroll
        for (int i = 0; i < WI; ++i) {
            const int mg = m0 + wr * (WI * 16) + i * 16 + lq * 4;
#pragma unroll
            for (int r = 0; r < 4; ++r) {
                const float v = (acc[i][j][r] + bvf) * outscale;
                if (OUT32)
                    ((float*)(first ? C0v : C1v))[(size_t)(mg + r) * ldc + nc] = v;
                else
                    ((f16*)(first ? C0v : C1v))[(size_t)(mg + r) * ldc + nc] = (f16)v;
            }
        }
    }
}

// ---------------------------------------------------------------------------
// PV step: 8 db-blocks of O += P @ V via hardware-transpose V reads.
// ---------------------------------------------------------------------------
#define SHUF8(x, y) __builtin_shufflevector(x, y, 0, 1, 2, 3, 4, 5, 6, 7)

template<int KC>
__device__ __forceinline__ void pv_step(const f16* __restrict__ PlW, unsigned vta,
                                        int l15, int lq, f32x4 (&acc)[8])
{
    const f16x8 pa = *(const f16x8*)&PlW[l15 * 64 + (((KC * 4 + lq) ^ (l15 & 7)) << 3)];
    {
        f16x4 a0 = tr16<0 * 2048 + KC * 1024 + 0>(vta);
        f16x4 b0 = tr16<0 * 2048 + KC * 1024 + 512>(vta);
        f16x4 a1 = tr16<1 * 2048 + KC * 1024 + 0>(vta);
        f16x4 b1 = tr16<1 * 2048 + KC * 1024 + 512>(vta);
        f16x4 a2 = tr16<2 * 2048 + KC * 1024 + 0>(vta);
        f16x4 b2 = tr16<2 * 2048 + KC * 1024 + 512>(vta);
        f16x4 a3 = tr16<3 * 2048 + KC * 1024 + 0>(vta);
        f16x4 b3 = tr16<3 * 2048 + KC * 1024 + 512>(vta);
        asm volatile("s_waitcnt lgkmcnt(0)" ::: "memory");
        __builtin_amdgcn_sched_barrier(0);
        __builtin_amdgcn_s_setprio(1);
        acc[0] = __builtin_amdgcn_mfma_f32_16x16x32_f16(pa, SHUF8(a0, b0), acc[0], 0, 0, 0);
        acc[1] = __builtin_amdgcn_mfma_f32_16x16x32_f16(pa, SHUF8(a1, b1), acc[1], 0, 0, 0);
        acc[2] = __builtin_amdgcn_mfma_f32_16x16x32_f16(pa, SHUF8(a2, b2), acc[2], 0, 0, 0);
        acc[3] = __builtin_amdgcn_mfma_f32_16x16x32_f16(pa, SHUF8(a3, b3), acc[3], 0, 0, 0);
        __builtin_amdgcn_s_setprio(0);
    }
    {
        f16x4 a4 = tr16<4 * 2048 + KC * 1024 + 0>(vta);
        f16x4 b4 = tr16<4 * 2048 + KC * 1024 + 512>(vta);
        f16x4 a5 = tr16<5 * 2048 + KC * 1024 + 0>(vta);
        f16x4 b5 = tr16<5 * 2048 + KC * 1024 + 512>(vta);
        f16x4 a6 = tr16<6 * 2048 + KC * 1024 + 0>(vta);
        f16x4 b6 = tr16<6 * 2048 + KC * 1024 + 512>(vta);
        f16x4 a7 = tr16<7 * 2048 + KC * 1024 + 0>(vta);
        f16x4 b7 = tr16<7 * 2048 + KC * 1024 + 512>(vta);
        asm volatile("s_waitcnt lgkmcnt(0)" ::: "memory");
        __builtin_amdgcn_sched_barrier(0);
        __builtin_amdgcn_s_setprio(1);
        acc[4] = __builtin_amdgcn_mfma_f32_16x16x32_f16(pa, SHUF8(a4, b4), acc[4], 0, 0, 0);
        acc[5] = __builtin_amdgcn_mfma_f32_16x16x32_f16(pa, SHUF8(a5, b5), acc[5], 0, 0, 0);
        acc[6] = __builtin_amdgcn_mfma_f32_16x16x32_f16(pa, SHUF8(a6, b6), acc[6], 0, 0, 0);
        acc[7] = __builtin_amdgcn_mfma_f32_16x16x32_f16(pa, SHUF8(a7, b7), acc[7], 0, 0, 0);
        __builtin_amdgcn_s_setprio(0);
    }
}

// ---------------------------------------------------------------------------
// fp16-MFMA flash attention: double-buffered K/V via global_load_lds with
// counted vmcnt + raw barriers (prefetch survives the barrier), tr-read V,
// defer-max softmax, deferred l-reduction, hi/lo f16 output.
// ---------------------------------------------------------------------------
__global__ __launch_bounds__(256) void flash_attn_mfma(
    const f16* __restrict__ Q, const f16* __restrict__ Kp,
    const f16* __restrict__ Vp, f16* __restrict__ AOh, f16* __restrict__ AOl)
{
    __shared__ f16 KsA[2][64 * 128];
    __shared__ f16 VtA[2][64 * 128];
    __shared__ f16 Pl[4][16 * 64];

    const int tid = threadIdx.x;
    const int w = tid >> 6, l = tid & 63;
    const int l15 = l & 15, lq = l >> 4;
    const int b = blockIdx.z, h = blockIdx.y, g = h >> 2;
    const int q0 = blockIdx.x << 6;

    const f16* Qb = Q + (size_t)(b * SEQ + q0) * D_MODEL + h * HD;
    const f16* Kb = Kp + (size_t)b * SEQ * GHD + g * HD;
    const f16* Vb = Vp + (size_t)b * SEQ * GHD + g * HD;

    // Q fragments (1/sqrt(128) pre-folded by the Q-projection GEMM)
    f16x8 aq[4];
    {
        const f16* qrow = Qb + (size_t)(w * 16 + l15) * D_MODEL;
#pragma unroll
        for (int c = 0; c < 4; ++c)
            aq[c] = *(const f16x8*)(qrow + c * 32 + lq * 8);
    }

    // staging source/dest (per-lane-permuted global source, linear LDS dest)
    lf16* Ks3 = (lf16*)&KsA[0][0];
    lf16* Vt3 = (lf16*)&VtA[0][0];
    const f16* ksrc[4]; lf16* kdst[4];
    const f16* vsrc[4]; lf16* vdst[4];
#pragma unroll
    for (int i = 0; i < 4; ++i) {
        const int s = tid + (i << 8);
        {
            const int row = s >> 4, ul = s & 15;
            ksrc[i] = Kb + (size_t)row * GHD + ((ul ^ (row & 7)) << 3);
            kdst[i] = Ks3 + s * 8;
        }
        {
            const int dbit = s & 1, kvlo = (s >> 1) & 3, vlq = (s >> 3) & 3;
            const int jh = (s >> 5) & 1, kc = (s >> 6) & 1, dsub = s >> 7;
            const int kv = (kc << 5) | (vlq << 3) | (jh << 2) | kvlo;
            vsrc[i] = Vb + (size_t)kv * GHD + ((dsub << 4) | (dbit << 3));
            vdst[i] = Vt3 + s * 8;
        }
    }
    const unsigned vta0 = (unsigned)(size_t)(Vt3 + l * 4);
    const unsigned vta1 = vta0 + 16384;   // second V buffer (bytes)
    const f16* PlW = &Pl[w][0];

    f32x4 acc_o[8];
#pragma unroll
    for (int i = 0; i < 8; ++i) acc_o[i] = (f32x4){0.f, 0.f, 0.f, 0.f};
    float m_r[4] = {-1e30f, -1e30f, -1e30f, -1e30f};
    float l_r[4] = {0.f, 0.f, 0.f, 0.f};   // per-lane partial row sums

    auto issue_tile = [&](int buf, int tile) {
        const size_t koff = (size_t)tile * 64 * GHD;
        const int KO = buf << 13;   // 8192 f16 per buffer
#pragma unroll
        for (int i = 0; i < 4; ++i)
            __builtin_amdgcn_global_load_lds((gvoid*)(ksrc[i] + koff),
                                             (lvoid*)(kdst[i] + KO), 16, 0, 0);
#pragma unroll
        for (int i = 0; i < 4; ++i)
            __builtin_amdgcn_global_load_lds((gvoid*)(vsrc[i] + koff),
                                             (lvoid*)(vdst[i] + KO), 16, 0, 0);
    };

    auto compute_tile = [&](const f16* KsB, unsigned vtaB) {
        // QK^T
        f32x4 sa[4];
        __builtin_amdgcn_s_setprio(1);
#pragma unroll
        for (int cb = 0; cb < 4; ++cb) {
            sa[cb] = (f32x4){0.f, 0.f, 0.f, 0.f};
#pragma unroll
            for (int c = 0; c < 4; ++c) {
                const int rk = cb * 16 + l15;
                const f16x8 bk = *(const f16x8*)&KsB[rk * 128 + (((c * 4 + lq) ^ (rk & 7)) << 3)];
                sa[cb] = __builtin_amdgcn_mfma_f32_16x16x32_f16(aq[c], bk, sa[cb], 0, 0, 0);
            }
        }
        __builtin_amdgcn_s_setprio(0);

        // online softmax with defer-max (skip rescale unless max grows > 8)
#pragma unroll
        for (int reg = 0; reg < 4; ++reg) {
            float mx = fmaxf(fmaxf(sa[0][reg], sa[1][reg]),
                             fmaxf(sa[2][reg], sa[3][reg]));
            mx = fmaxf(mx, __shfl_xor(mx, 1));
            mx = fmaxf(mx, __shfl_xor(mx, 2));
            mx = fmaxf(mx, __shfl_xor(mx, 4));
            mx = fmaxf(mx, __shfl_xor(mx, 8));
            if (mx > m_r[reg] + 8.f) {           // uniform within 16-lane row group
                const float alpha = __expf(m_r[reg] - mx);
                m_r[reg] = mx;
                l_r[reg] *= alpha;
#pragma unroll
                for (int db = 0; db < 8; ++db) acc_o[db][reg] *= alpha;
            }
            const int r = lq * 4 + reg;
            float sum = 0.f;
#pragma unroll
            for (int cb = 0; cb < 4; ++cb) {
                const float p = __expf(sa[cb][reg] - m_r[reg]);
                sum += p;
                const int col = cb * 16 + l15;
                Pl[w][r * 64 + (((col >> 3) ^ (r & 7)) << 3) + (col & 7)] = (f16)p;
            }
            l_r[reg] += sum;                     // per-lane partial; reduce at end
        }

        // PV via hardware transpose reads
        pv_step<0>(PlW, vtaB, l15, lq, acc_o);
        pv_step<1>(PlW, vtaB, l15, lq, acc_o);
    };

    // ---- pipelined main loop: 32 tiles, unrolled by 2 (static buffers) ----
    issue_tile(0, 0);
#pragma unroll 1
    for (int t2 = 0; t2 < 16; ++t2) {
        const int kt0 = t2 << 1;
        issue_tile(1, kt0 + 1);
        WAIT_VM8();                      // tile kt0 (own 8 oldest) complete
        BAR();
        compute_tile(&KsA[0][0], vta0);
        BAR();                           // all waves done reading buf0
        if (t2 < 15) {
            issue_tile(0, kt0 + 2);
            WAIT_VM8();                  // tile kt0+1 complete
        } else {
            WAIT_VM0();
        }
        BAR();
        compute_tile(&KsA[1][0], vta1);
        BAR();                           // all waves done reading buf1
    }

    // ---- epilogue: reduce l across the 16-lane row group, normalize, store
    float inv_l[4];
#pragma unroll
    for (int reg = 0; reg < 4; ++reg) {
        float s = l_r[reg];
        s += __shfl_xor(s, 1);
        s += __shfl_xor(s, 2);
        s += __shfl_xor(s, 4);
        s += __shfl_xor(s, 8);
        inv_l[reg] = 1.f / s;
    }
    const size_t obase = (size_t)(b * SEQ + q0 + w * 16) * D_MODEL + h * HD;
#pragma unroll
    for (int db = 0; db < 8; ++db) {
#pragma unroll
        for (int reg = 0; reg < 4; ++reg) {
            const size_t off = obase + (size_t)(lq * 4 + reg) * D_MODEL + db * 16 + l15;
            const float v = acc_o[db][reg] * inv_l[reg];
            const f16 hh = (f16)v;
            AOh[off] = hh;
            AOl[off] = (f16)(v - (float)hh);
        }
    }
}

extern "C" void kernel_launch(void* const* d_in, const int* in_sizes, int n_in,
                              void* d_out, int out_size, void* d_ws, size_t ws_size,
                              hipStream_t stream)
{
    const float* x  = (const float*)d_in[0];
    const float* Wq = (const float*)d_in[1];
    const float* bq = (const float*)d_in[2];
    const float* Wk = (const float*)d_in[3];
    const float* bk = (const float*)d_in[4];
    const float* Wv = (const float*)d_in[5];
    const float* bv = (const float*)d_in[6];
    const float* Wo = (const float*)d_in[7];
    const float* bo = (const float*)d_in[8];
    float* out = (float*)d_out;

    // workspace (f16 units), total 41,943,040 f16 = 83.9 MB.
    // AOh/AOl alias xh/xl (x dead after QKV GEMMs); Wo^T reuses Wq^T slot.
    f16* base   = (f16*)d_ws;
    f16* xh     = base;                 // 8388608
    f16* xl     = base + 8388608;       // 8388608
    f16* WkvT_h = base + 16777216;      // 2097152
    f16* WkvT_l = base + 18874368;      // 2097152
    f16* WqoT_h = base + 20971520;      // 4194304
    f16* WqoT_l = base + 25165824;      // 4194304
    f16* Qp     = base + 29360128;      // 8388608
    f16* Kp     = base + 37748736;      // 2097152
    f16* Vp     = base + 39845888;      // 2097152 -> end 41943040
    f16* AOh    = xh;
    f16* AOl    = xl;

    const dim3 blk(256);
    const float qscale = 0.08838834764831845f;   // 1/sqrt(128)

    split_f32<<<dim3(M_TOT * D_MODEL / 8 / 256), blk, 0, stream>>>(x, xh, xl);
    transpose_split<<<dim3(64, 64), blk, 0, stream>>>(Wq, WqoT_h, WqoT_l, 2048, 2048, 0);
    transpose_split<<<dim3(16, 64), blk, 0, stream>>>(Wk, WkvT_h, WkvT_l, 2048, 512, 0);
    transpose_split<<<dim3(16, 64), blk, 0, stream>>>(Wv, WkvT_h, WkvT_l, 2048, 512, 512);

    gemm_split<128, false><<<dim3(16, 32), blk, 0, stream>>>(
        xh, xl, WqoT_h, WqoT_l, bq, bq, Qp, Qp, 2048, 2048, 2048, 2048, qscale);
    gemm_split<64, false><<<dim3(16, 32), blk, 0, stream>>>(
        xh, xl, WkvT_h, WkvT_l, bk, bv, Kp, Vp, 512, 512, 512, 2048, 1.0f);

    // Wo^T into the (now dead) Wq^T slot, before attention overwrites xh/xl
    transpose_split<<<dim3(64, 64), blk, 0, stream>>>(Wo, WqoT_h, WqoT_l, 2048, 2048, 0);

    flash_attn_mfma<<<dim3(SEQ / 64, NQH, B_SZ), blk, 0, stream>>>(Qp, Kp, Vp, AOh, AOl);

    gemm_split<128, true><<<dim3(16, 32), blk, 0, stream>>>(
        AOh, AOl, WqoT_h, WqoT_l, bo, bo, out, out, 2048, 2048, 2048, 2048, 1.0f);
}

// Round 6
// 445.960 us; speedup vs baseline: 7.9025x; 1.0938x over previous
//
#include <hip/hip_runtime.h>

#define D_MODEL 2048
#define GHD 512        // NUM_KV_GROUPS * HEAD_DIM
#define HD 128
#define NQH 16
#define B_SZ 2
#define SEQ 2048
#define M_TOT (B_SZ * SEQ)   // 4096

typedef _Float16 f16;
typedef _Float16 f16x4 __attribute__((ext_vector_type(4)));
typedef _Float16 f16x8 __attribute__((ext_vector_type(8)));
typedef float f32x4 __attribute__((ext_vector_type(4)));

typedef const __attribute__((address_space(1))) void gvoid;
typedef __attribute__((address_space(3))) void lvoid;
typedef __attribute__((address_space(3))) f16 lf16;

// raw barrier (no vmcnt(0) drain) with compiler fences
#define BAR() do { asm volatile("" ::: "memory"); \
                   __builtin_amdgcn_s_barrier();  \
                   asm volatile("" ::: "memory"); } while (0)
#define WAIT_VM8() asm volatile("s_waitcnt vmcnt(8)" ::: "memory")
#define WAIT_VM0() asm volatile("s_waitcnt vmcnt(0)" ::: "memory")
#define WAIT_LGKM(N) do { asm volatile("s_waitcnt lgkmcnt(" #N ")" ::: "memory"); \
                          __builtin_amdgcn_sched_barrier(0); } while (0)

// hardware transpose read: with per-lane addr = base + l*8B, lane l elem j
// reads f16 at base_f16[OFF/2 + (l>>4)*64 + j*16 + (l&15)]
template<int OFF>
__device__ __forceinline__ f16x4 tr16(unsigned a) {
    f16x4 d;
    asm volatile("ds_read_b64_tr_b16 %0, %1 offset:%2"
                 : "=v"(d) : "v"(a), "i"(OFF));
    return d;
}

// ---------------------------------------------------------------------------
// x (fp32) -> hi/lo f16 split, elementwise
// ---------------------------------------------------------------------------
__global__ __launch_bounds__(256) void split_f32(
    const float* __restrict__ X, f16* __restrict__ Xh, f16* __restrict__ Xl)
{
    const size_t i = ((size_t)blockIdx.x * 256 + threadIdx.x) * 8;
    const float4 v0 = *(const float4*)(X + i);
    const float4 v1 = *(const float4*)(X + i + 4);
    const float a[8] = {v0.x, v0.y, v0.z, v0.w, v1.x, v1.y, v1.z, v1.w};
    f16x8 h, lo;
#pragma unroll
    for (int e = 0; e < 8; ++e) {
        h[e] = (f16)a[e];
        lo[e] = (f16)(a[e] - (float)h[e]);
    }
    *(f16x8*)(Xh + i) = h;
    *(f16x8*)(Xl + i) = lo;
}

// ---------------------------------------------------------------------------
// Transpose + hi/lo fp16 split: W[K][N] fp32 -> Th/Tl[(row_off+n)][K] f16
// ---------------------------------------------------------------------------
__global__ __launch_bounds__(256) void transpose_split(
    const float* __restrict__ W, f16* __restrict__ Th, f16* __restrict__ Tl,
    int K, int N, int row_off)
{
    __shared__ float Ls[32][33];
    const int t = threadIdx.x;
    const int n0 = blockIdx.x << 5, k0 = blockIdx.y << 5;
    {
        const int kr = t >> 3, nq = (t & 7) << 2;
        const float4 v = *(const float4*)&W[(size_t)(k0 + kr) * N + n0 + nq];
        Ls[kr][nq + 0] = v.x; Ls[kr][nq + 1] = v.y;
        Ls[kr][nq + 2] = v.z; Ls[kr][nq + 3] = v.w;
    }
    __syncthreads();
    const int nr = t >> 3, kq = (t & 7) << 2;
    f16x4 hv, lv;
#pragma unroll
    for (int e = 0; e < 4; ++e) {
        const float a = Ls[kq + e][nr];
        const f16 h = (f16)a;
        hv[e] = h;
        lv[e] = (f16)(a - (float)h);
    }
    const size_t off = (size_t)(row_off + n0 + nr) * K + k0 + kq;
    *(f16x4*)&Th[off] = hv;
    *(f16x4*)&Tl[off] = lv;
}

// ---------------------------------------------------------------------------
// Split-precision MFMA GEMM, pre-split f16 A and B (W^T) inputs.
// 3 terms: AhBh + AlBh + AhBl. BM=128, BK=32, 256 threads (4 waves).
// ---------------------------------------------------------------------------
template<int BN, bool OUT32>
__global__ __launch_bounds__(256) void gemm_split(
    const f16* __restrict__ Agh, const f16* __restrict__ Agl,
    const f16* __restrict__ BTh, const f16* __restrict__ BTl,
    const float* __restrict__ bias0, const float* __restrict__ bias1,
    void* __restrict__ C0v, void* __restrict__ C1v,
    int Nsplit, int ld0, int ld1, int K, float outscale)
{
    constexpr int WN = BN / 64;
    constexpr int WM = 4 / WN;
    constexpr int WI = 128 / (WM * 16);
    constexpr int LDK = 40;
    constexpr int NB = (BN * 4) / 256;

    __shared__ f16 Ah[128 * LDK], Al[128 * LDK];
    __shared__ f16 Bh[BN * LDK],  Bl[BN * LDK];

    const int tid = threadIdx.x;
    const int l = tid & 63, w = tid >> 6;
    const int l15 = l & 15, lq = l >> 4;
    const int wr = w / WN, wc = w % WN;
    const int m0 = blockIdx.y << 7;
    const int n0 = blockIdx.x * BN;

    f32x4 acc[WI][4];
#pragma unroll
    for (int i = 0; i < WI; ++i)
#pragma unroll
        for (int j = 0; j < 4; ++j) acc[i][j] = (f32x4){0.f, 0.f, 0.f, 0.f};

    const int ar  = tid >> 2;
    const int auk = (tid & 3) << 3;
    const f16* Ahp = Agh + (size_t)(m0 + ar) * K + auk;
    const f16* Alp = Agl + (size_t)(m0 + ar) * K + auk;
    const int bnr = tid >> 2, buk = (tid & 3) << 3;
    const f16* Bhp = BTh + (size_t)(n0 + bnr) * K + buk;
    const f16* Blp = BTl + (size_t)(n0 + bnr) * K + buk;

    f16x8 a0h = *(const f16x8*)(Ahp);
    f16x8 a1h = *(const f16x8*)(Ahp + (size_t)64 * K);
    f16x8 a0l = *(const f16x8*)(Alp);
    f16x8 a1l = *(const f16x8*)(Alp + (size_t)64 * K);
    f16x8 bhv[NB], blv[NB];
#pragma unroll
    for (int it = 0; it < NB; ++it) {
        bhv[it] = *(const f16x8*)(Bhp + (size_t)(it * 64) * K);
        blv[it] = *(const f16x8*)(Blp + (size_t)(it * 64) * K);
    }

    for (int k0 = 0; k0 < K; k0 += 32) {
        __syncthreads();
        *(f16x8*)&Ah[ar * LDK + auk] = a0h;
        *(f16x8*)&Ah[(ar + 64) * LDK + auk] = a1h;
        *(f16x8*)&Al[ar * LDK + auk] = a0l;
        *(f16x8*)&Al[(ar + 64) * LDK + auk] = a1l;
#pragma unroll
        for (int it = 0; it < NB; ++it) {
            *(f16x8*)&Bh[(bnr + it * 64) * LDK + buk] = bhv[it];
            *(f16x8*)&Bl[(bnr + it * 64) * LDK + buk] = blv[it];
        }
        __syncthreads();

        const int kn = k0 + 32;
        a0h = *(const f16x8*)(Ahp + kn);
        a1h = *(const f16x8*)(Ahp + (size_t)64 * K + kn);
        a0l = *(const f16x8*)(Alp + kn);
        a1l = *(const f16x8*)(Alp + (size_t)64 * K + kn);
#pragma unroll
        for (int it = 0; it < NB; ++it) {
            bhv[it] = *(const f16x8*)(Bhp + (size_t)(it * 64) * K + kn);
            blv[it] = *(const f16x8*)(Blp + (size_t)(it * 64) * K + kn);
        }

        f16x8 afh[WI], afl[WI];
#pragma unroll
        for (int i = 0; i < WI; ++i) {
            const int row = wr * (WI * 16) + i * 16 + l15;
            afh[i] = *(const f16x8*)&Ah[row * LDK + lq * 8];
            afl[i] = *(const f16x8*)&Al[row * LDK + lq * 8];
        }
#pragma unroll
        for (int j = 0; j < 4; ++j) {
            const int bn = wc * 64 + j * 16 + l15;
            const f16x8 bfh = *(const f16x8*)&Bh[bn * LDK + lq * 8];
            const f16x8 bfl = *(const f16x8*)&Bl[bn * LDK + lq * 8];
#pragma unroll
            for (int i = 0; i < WI; ++i)
                acc[i][j] = __builtin_amdgcn_mfma_f32_16x16x32_f16(afh[i], bfh, acc[i][j], 0, 0, 0);
#pragma unroll
            for (int i = 0; i < WI; ++i)
                acc[i][j] = __builtin_amdgcn_mfma_f32_16x16x32_f16(afl[i], bfh, acc[i][j], 0, 0, 0);
#pragma unroll
            for (int i = 0; i < WI; ++i)
                acc[i][j] = __builtin_amdgcn_mfma_f32_16x16x32_f16(afh[i], bfl, acc[i][j], 0, 0, 0);
        }
    }

#pragma unroll
    for (int j = 0; j < 4; ++j) {
        const int ng = n0 + wc * 64 + j * 16 + l15;
        const bool first = ng < Nsplit;
        const float bvf = first ? bias0[ng] : bias1[ng - Nsplit];
        const int nc = first ? ng : ng - Nsplit;
        const int ldc = first ? ld0 : ld1;
#pragma unroll
        for (int i = 0; i < WI; ++i) {
            const int mg = m0 + wr * (WI * 16) + i * 16 + lq * 4;
#pragma unroll
            for (int r = 0; r < 4; ++r) {
                const float v = (acc[i][j][r] + bvf) * outscale;
                if (OUT32)
                    ((float*)(first ? C0v : C1v))[(size_t)(mg + r) * ldc + nc] = v;
                else
                    ((f16*)(first ? C0v : C1v))[(size_t)(mg + r) * ldc + nc] = (f16)v;
            }
        }
    }
}

#define SHUF8(x, y) __builtin_shufflevector(x, y, 0, 1, 2, 3, 4, 5, 6, 7)

// ---------------------------------------------------------------------------
// fp16-MFMA flash attention v3: 4 waves x 32 q-rows (QBLK=128), KV tile 64,
// double-buffered K/V via global_load_lds + counted vmcnt + raw barriers,
// tr16 V *and* tr16 P (transposed P store: 8 ds_write_b64, conflict-free),
// per-db-pipelined PV with counted lgkmcnt, defer-max softmax,
// deferred l-reduction, hi/lo f16 output.
// ---------------------------------------------------------------------------
__global__ __launch_bounds__(256, 2) void flash_attn_mfma(
    const f16* __restrict__ Q, const f16* __restrict__ Kp,
    const f16* __restrict__ Vp, f16* __restrict__ AOh, f16* __restrict__ AOl)
{
    __shared__ f16 KsA[2][64 * 128];   // 32 KB
    __shared__ f16 VtA[2][64 * 128];   // 32 KB (tr16 subtiled)
    __shared__ f16 Pt[4][2048];        // 16 KB per-wave transposed P

    const int tid = threadIdx.x;
    const int w = tid >> 6, l = tid & 63;
    const int l15 = l & 15, lq = l >> 4;
    const int b = blockIdx.z, h = blockIdx.y, g = h >> 2;
    const int q0 = blockIdx.x << 7;    // 128 q-rows per block

    const f16* Qb = Q + (size_t)(b * SEQ + q0) * D_MODEL + h * HD;
    const f16* Kb = Kp + (size_t)b * SEQ * GHD + g * HD;
    const f16* Vb = Vp + (size_t)b * SEQ * GHD + g * HD;

    // Q fragments: wave owns rows [w*32, w*32+32) as 2 groups of 16
    f16x8 aq[2][4];
#pragma unroll
    for (int rg = 0; rg < 2; ++rg) {
        const f16* qrow = Qb + (size_t)(w * 32 + rg * 16 + l15) * D_MODEL;
#pragma unroll
        for (int c = 0; c < 4; ++c)
            aq[rg][c] = *(const f16x8*)(qrow + c * 32 + lq * 8);
    }

    // staging addresses (per-lane-permuted global source, linear LDS dest)
    lf16* Ks3 = (lf16*)&KsA[0][0];
    lf16* Vt3 = (lf16*)&VtA[0][0];
    const f16* ksrc[4]; lf16* kdst[4];
    const f16* vsrc[4]; lf16* vdst[4];
#pragma unroll
    for (int i = 0; i < 4; ++i) {
        const int s = tid + (i << 8);
        {
            const int row = s >> 4, ul = s & 15;
            ksrc[i] = Kb + (size_t)row * GHD + ((ul ^ (row & 7)) << 3);
            kdst[i] = Ks3 + s * 8;
        }
        {
            const int dbit = s & 1, kvlo = (s >> 1) & 3, vlq = (s >> 3) & 3;
            const int jh = (s >> 5) & 1, kc = (s >> 6) & 1, dsub = s >> 7;
            const int kv = (kc << 5) | (vlq << 3) | (jh << 2) | kvlo;
            vsrc[i] = Vb + (size_t)kv * GHD + ((dsub << 4) | (dbit << 3));
            vdst[i] = Vt3 + s * 8;
        }
    }
    const unsigned vta0 = (unsigned)(size_t)(Vt3 + l * 4);
    const unsigned vta1 = vta0 + 16384;
    f16* PtW = &Pt[w][0];
    const unsigned pta = (unsigned)(size_t)((lf16*)PtW + l * 4);
    // P-write lane-constant part (f16 units)
    const int pbl = ((l15 >> 2) & 1) * 256 + (l15 >> 3) * 64 + (l15 & 3) * 16 + lq * 4;

    f32x4 acc_o[2][8];
#pragma unroll
    for (int rg = 0; rg < 2; ++rg)
#pragma unroll
        for (int i = 0; i < 8; ++i) acc_o[rg][i] = (f32x4){0.f, 0.f, 0.f, 0.f};
    float m_r[2][4], l_r[2][4];
#pragma unroll
    for (int rg = 0; rg < 2; ++rg)
#pragma unroll
        for (int r = 0; r < 4; ++r) { m_r[rg][r] = -1e30f; l_r[rg][r] = 0.f; }

    auto issue_tile = [&](int buf, int tile) {
        const size_t koff = (size_t)tile * 64 * GHD;
        const int KO = buf << 13;
#pragma unroll
        for (int i = 0; i < 4; ++i)
            __builtin_amdgcn_global_load_lds((gvoid*)(ksrc[i] + koff),
                                             (lvoid*)(kdst[i] + KO), 16, 0, 0);
#pragma unroll
        for (int i = 0; i < 4; ++i)
            __builtin_amdgcn_global_load_lds((gvoid*)(vsrc[i] + koff),
                                             (lvoid*)(vdst[i] + KO), 16, 0, 0);
    };

    auto compute_tile = [&](const f16* KsB, unsigned vtaB) {
        // ---- QK^T: S[32][64] per wave; each K-frag feeds both row-groups
        f32x4 sa[2][4];
        __builtin_amdgcn_s_setprio(1);
#pragma unroll
        for (int cb = 0; cb < 4; ++cb) {
            sa[0][cb] = (f32x4){0.f, 0.f, 0.f, 0.f};
            sa[1][cb] = (f32x4){0.f, 0.f, 0.f, 0.f};
#pragma unroll
            for (int c = 0; c < 4; ++c) {
                const int rk = cb * 16 + l15;
                const f16x8 bk = *(const f16x8*)&KsB[rk * 128 + (((c * 4 + lq) ^ (rk & 7)) << 3)];
                sa[0][cb] = __builtin_amdgcn_mfma_f32_16x16x32_f16(aq[0][c], bk, sa[0][cb], 0, 0, 0);
                sa[1][cb] = __builtin_amdgcn_mfma_f32_16x16x32_f16(aq[1][c], bk, sa[1][cb], 0, 0, 0);
            }
        }
        __builtin_amdgcn_s_setprio(0);

        // ---- online softmax (defer-max); P stored transposed as 8 b64 writes
#pragma unroll
        for (int rg = 0; rg < 2; ++rg) {
#pragma unroll
            for (int reg = 0; reg < 4; ++reg) {
                float mx = fmaxf(fmaxf(sa[rg][0][reg], sa[rg][1][reg]),
                                 fmaxf(sa[rg][2][reg], sa[rg][3][reg]));
                mx = fmaxf(mx, __shfl_xor(mx, 1));
                mx = fmaxf(mx, __shfl_xor(mx, 2));
                mx = fmaxf(mx, __shfl_xor(mx, 4));
                mx = fmaxf(mx, __shfl_xor(mx, 8));
                if (mx > m_r[rg][reg] + 8.f) {
                    const float alpha = __expf(m_r[rg][reg] - mx);
                    m_r[rg][reg] = mx;
                    l_r[rg][reg] *= alpha;
#pragma unroll
                    for (int db = 0; db < 8; ++db) acc_o[rg][db][reg] *= alpha;
                }
            }
#pragma unroll
            for (int cb = 0; cb < 4; ++cb) {
                f16x4 w4;
#pragma unroll
                for (int reg = 0; reg < 4; ++reg) {
                    const float p = __expf(sa[rg][cb][reg] - m_r[rg][reg]);
                    l_r[rg][reg] += p;
                    w4[reg] = (f16)p;
                }
                *(f16x4*)&PtW[rg * 1024 + (cb >> 1) * 512 + (cb & 1) * 128 + pbl] = w4;
            }
        }

        // ---- PV: per-db pipelined, counted lgkmcnt
        asm volatile("" ::: "memory");   // pin P-writes before the tr16 reads
        // P A-frags: 16 tr16 (in-order DS retires the P-writes first)
        f16x8 pa[2][2];
#pragma unroll
        for (int rg = 0; rg < 2; ++rg)
#pragma unroll
            for (int kc = 0; kc < 2; ++kc) {
                f16x4 p0, p1;
                if (rg == 0 && kc == 0) { p0 = tr16<0>(pta);    p1 = tr16<512>(pta); }
                if (rg == 0 && kc == 1) { p0 = tr16<1024>(pta); p1 = tr16<1536>(pta); }
                if (rg == 1 && kc == 0) { p0 = tr16<2048>(pta); p1 = tr16<2560>(pta); }
                if (rg == 1 && kc == 1) { p0 = tr16<3072>(pta); p1 = tr16<3584>(pta); }
                pa[rg][kc] = SHUF8(p0, p1);
            }

        f16x8 v0k0, v0k1;
        {   // db = 0 V-frags
            f16x4 a0 = tr16<0>(vtaB),    b0 = tr16<512>(vtaB);
            f16x4 a1 = tr16<1024>(vtaB), b1 = tr16<1536>(vtaB);
            WAIT_LGKM(4);                // pa (16) done; db0 V in flight
            v0k0 = SHUF8(a0, b0); v0k1 = SHUF8(a1, b1);
        }
#pragma unroll
        for (int db = 0; db < 8; ++db) {
            f16x8 n0, n1;
            if (db < 7) {
                // issue V(db+1): offsets (db+1)*2048 + kc*1024 + h*512
                f16x4 a0, b0, a1, b1;
                switch (db) {
                case 0: a0=tr16<2048>(vtaB);  b0=tr16<2560>(vtaB);  a1=tr16<3072>(vtaB);  b1=tr16<3584>(vtaB);  break;
                case 1: a0=tr16<4096>(vtaB);  b0=tr16<4608>(vtaB);  a1=tr16<5120>(vtaB);  b1=tr16<5632>(vtaB);  break;
                case 2: a0=tr16<6144>(vtaB);  b0=tr16<6656>(vtaB);  a1=tr16<7168>(vtaB);  b1=tr16<7680>(vtaB);  break;
                case 3: a0=tr16<8192>(vtaB);  b0=tr16<8704>(vtaB);  a1=tr16<9216>(vtaB);  b1=tr16<9728>(vtaB);  break;
                case 4: a0=tr16<10240>(vtaB); b0=tr16<10752>(vtaB); a1=tr16<11264>(vtaB); b1=tr16<11776>(vtaB); break;
                case 5: a0=tr16<12288>(vtaB); b0=tr16<12800>(vtaB); a1=tr16<13312>(vtaB); b1=tr16<13824>(vtaB); break;
                default:a0=tr16<14336>(vtaB); b0=tr16<14848>(vtaB); a1=tr16<15360>(vtaB); b1=tr16<15872>(vtaB); break;
                }
                WAIT_LGKM(4);            // V(db) done, V(db+1) in flight
                n0 = SHUF8(a0, b0); n1 = SHUF8(a1, b1);
            } else {
                WAIT_LGKM(0);
            }
            __builtin_amdgcn_s_setprio(1);
            acc_o[0][db] = __builtin_amdgcn_mfma_f32_16x16x32_f16(pa[0][0], v0k0, acc_o[0][db], 0, 0, 0);
            acc_o[1][db] = __builtin_amdgcn_mfma_f32_16x16x32_f16(pa[1][0], v0k0, acc_o[1][db], 0, 0, 0);
            acc_o[0][db] = __builtin_amdgcn_mfma_f32_16x16x32_f16(pa[0][1], v0k1, acc_o[0][db], 0, 0, 0);
            acc_o[1][db] = __builtin_amdgcn_mfma_f32_16x16x32_f16(pa[1][1], v0k1, acc_o[1][db], 0, 0, 0);
            __builtin_amdgcn_s_setprio(0);
            if (db < 7) { v0k0 = n0; v0k1 = n1; }
        }
    };

    // ---- pipelined main loop: 32 KV tiles, unrolled by 2 (static buffers)
    issue_tile(0, 0);
#pragma unroll 1
    for (int t2 = 0; t2 < 16; ++t2) {
        const int kt0 = t2 << 1;
        issue_tile(1, kt0 + 1);
        WAIT_VM8();
        BAR();
        compute_tile(&KsA[0][0], vta0);
        BAR();
        if (t2 < 15) {
            issue_tile(0, kt0 + 2);
            WAIT_VM8();
        } else {
            WAIT_VM0();
        }
        BAR();
        compute_tile(&KsA[1][0], vta1);
        BAR();
    }

    // ---- epilogue: reduce l across the 16-lane row group, normalize, store
    const size_t obase = (size_t)(b * SEQ + q0 + w * 32) * D_MODEL + h * HD;
#pragma unroll
    for (int rg = 0; rg < 2; ++rg) {
        float inv_l[4];
#pragma unroll
        for (int reg = 0; reg < 4; ++reg) {
            float s = l_r[rg][reg];
            s += __shfl_xor(s, 1);
            s += __shfl_xor(s, 2);
            s += __shfl_xor(s, 4);
            s += __shfl_xor(s, 8);
            inv_l[reg] = 1.f / s;
        }
#pragma unroll
        for (int db = 0; db < 8; ++db) {
#pragma unroll
            for (int reg = 0; reg < 4; ++reg) {
                const size_t off = obase + (size_t)(rg * 16 + lq * 4 + reg) * D_MODEL + db * 16 + l15;
                const float v = acc_o[rg][db][reg] * inv_l[reg];
                const f16 hh = (f16)v;
                AOh[off] = hh;
                AOl[off] = (f16)(v - (float)hh);
            }
        }
    }
}

extern "C" void kernel_launch(void* const* d_in, const int* in_sizes, int n_in,
                              void* d_out, int out_size, void* d_ws, size_t ws_size,
                              hipStream_t stream)
{
    const float* x  = (const float*)d_in[0];
    const float* Wq = (const float*)d_in[1];
    const float* bq = (const float*)d_in[2];
    const float* Wk = (const float*)d_in[3];
    const float* bk = (const float*)d_in[4];
    const float* Wv = (const float*)d_in[5];
    const float* bv = (const float*)d_in[6];
    const float* Wo = (const float*)d_in[7];
    const float* bo = (const float*)d_in[8];
    float* out = (float*)d_out;

    // workspace (f16 units), total 41,943,040 f16 = 83.9 MB.
    f16* base   = (f16*)d_ws;
    f16* xh     = base;                 // 8388608
    f16* xl     = base + 8388608;       // 8388608
    f16* WkvT_h = base + 16777216;      // 2097152
    f16* WkvT_l = base + 18874368;      // 2097152
    f16* WqoT_h = base + 20971520;      // 4194304
    f16* WqoT_l = base + 25165824;      // 4194304
    f16* Qp     = base + 29360128;      // 8388608
    f16* Kp     = base + 37748736;      // 2097152
    f16* Vp     = base + 39845888;      // 2097152 -> end 41943040
    f16* AOh    = xh;
    f16* AOl    = xl;

    const dim3 blk(256);
    const float qscale = 0.08838834764831845f;   // 1/sqrt(128)

    split_f32<<<dim3(M_TOT * D_MODEL / 8 / 256), blk, 0, stream>>>(x, xh, xl);
    transpose_split<<<dim3(64, 64), blk, 0, stream>>>(Wq, WqoT_h, WqoT_l, 2048, 2048, 0);
    transpose_split<<<dim3(16, 64), blk, 0, stream>>>(Wk, WkvT_h, WkvT_l, 2048, 512, 0);
    transpose_split<<<dim3(16, 64), blk, 0, stream>>>(Wv, WkvT_h, WkvT_l, 2048, 512, 512);

    gemm_split<128, false><<<dim3(16, 32), blk, 0, stream>>>(
        xh, xl, WqoT_h, WqoT_l, bq, bq, Qp, Qp, 2048, 2048, 2048, 2048, qscale);
    gemm_split<64, false><<<dim3(16, 32), blk, 0, stream>>>(
        xh, xl, WkvT_h, WkvT_l, bk, bv, Kp, Vp, 512, 512, 512, 2048, 1.0f);

    transpose_split<<<dim3(64, 64), blk, 0, stream>>>(Wo, WqoT_h, WqoT_l, 2048, 2048, 0);

    flash_attn_mfma<<<dim3(SEQ / 128, NQH, B_SZ), blk, 0, stream>>>(Qp, Kp, Vp, AOh, AOl);

    gemm_split<128, true><<<dim3(16, 32), blk, 0, stream>>>(
        AOh, AOl, WqoT_h, WqoT_l, bo, bo, out, out, 2048, 2048, 2048, 2048, 1.0f);
}

// Round 7
// 408.248 us; speedup vs baseline: 8.6325x; 1.0924x over previous
//
#include <hip/hip_runtime.h>

#define D_MODEL 2048
#define GHD 512        // NUM_KV_GROUPS * HEAD_DIM
#define HD 128
#define NQH 16
#define B_SZ 2
#define SEQ 2048
#define M_TOT (B_SZ * SEQ)   // 4096

typedef _Float16 f16;
typedef _Float16 f16x4 __attribute__((ext_vector_type(4)));
typedef _Float16 f16x8 __attribute__((ext_vector_type(8)));
typedef float f32x4 __attribute__((ext_vector_type(4)));

typedef const __attribute__((address_space(1))) void gvoid;
typedef __attribute__((address_space(3))) void lvoid;
typedef __attribute__((address_space(3))) f16 lf16;

// raw barrier (no vmcnt(0) drain) with compiler fences
#define BAR() do { asm volatile("" ::: "memory"); \
                   __builtin_amdgcn_s_barrier();  \
                   asm volatile("" ::: "memory"); } while (0)
#define WAIT_VM8() asm volatile("s_waitcnt vmcnt(8)" ::: "memory")
#define WAIT_VM0() asm volatile("s_waitcnt vmcnt(0)" ::: "memory")
#define WAIT_LGKM(N) do { asm volatile("s_waitcnt lgkmcnt(" #N ")" ::: "memory"); \
                          __builtin_amdgcn_sched_barrier(0); } while (0)

// hardware transpose read: with per-lane addr = base + l*8B, lane l elem j
// reads f16 at base_f16[OFF/2 + (l>>4)*64 + j*16 + (l&15)]
template<int OFF>
__device__ __forceinline__ f16x4 tr16(unsigned a) {
    f16x4 d;
    asm volatile("ds_read_b64_tr_b16 %0, %1 offset:%2"
                 : "=v"(d) : "v"(a), "i"(OFF));
    return d;
}

// ---------------------------------------------------------------------------
// x (fp32) -> hi/lo f16 split, elementwise
// ---------------------------------------------------------------------------
__global__ __launch_bounds__(256) void split_f32(
    const float* __restrict__ X, f16* __restrict__ Xh, f16* __restrict__ Xl)
{
    const size_t i = ((size_t)blockIdx.x * 256 + threadIdx.x) * 8;
    const float4 v0 = *(const float4*)(X + i);
    const float4 v1 = *(const float4*)(X + i + 4);
    const float a[8] = {v0.x, v0.y, v0.z, v0.w, v1.x, v1.y, v1.z, v1.w};
    f16x8 h, lo;
#pragma unroll
    for (int e = 0; e < 8; ++e) {
        h[e] = (f16)a[e];
        lo[e] = (f16)(a[e] - (float)h[e]);
    }
    *(f16x8*)(Xh + i) = h;
    *(f16x8*)(Xl + i) = lo;
}

// ---------------------------------------------------------------------------
// Transpose + hi/lo fp16 split: W[K][N] fp32 -> Th/Tl[(row_off+n)][K] f16
// ---------------------------------------------------------------------------
__global__ __launch_bounds__(256) void transpose_split(
    const float* __restrict__ W, f16* __restrict__ Th, f16* __restrict__ Tl,
    int K, int N, int row_off)
{
    __shared__ float Ls[32][33];
    const int t = threadIdx.x;
    const int n0 = blockIdx.x << 5, k0 = blockIdx.y << 5;
    {
        const int kr = t >> 3, nq = (t & 7) << 2;
        const float4 v = *(const float4*)&W[(size_t)(k0 + kr) * N + n0 + nq];
        Ls[kr][nq + 0] = v.x; Ls[kr][nq + 1] = v.y;
        Ls[kr][nq + 2] = v.z; Ls[kr][nq + 3] = v.w;
    }
    __syncthreads();
    const int nr = t >> 3, kq = (t & 7) << 2;
    f16x4 hv, lv;
#pragma unroll
    for (int e = 0; e < 4; ++e) {
        const float a = Ls[kq + e][nr];
        const f16 h = (f16)a;
        hv[e] = h;
        lv[e] = (f16)(a - (float)h);
    }
    const size_t off = (size_t)(row_off + n0 + nr) * K + k0 + kq;
    *(f16x4*)&Th[off] = hv;
    *(f16x4*)&Tl[off] = lv;
}

// ---------------------------------------------------------------------------
// Split-precision MFMA GEMM, pre-split f16 A and B (W^T) inputs.
// 3 terms: AhBh + AlBh + AhBl. BM=128, BK=32, 256 threads (4 waves).
// XCD-aware block swizzle (T1): nwg is always 512 here (divisible by 8).
// ---------------------------------------------------------------------------
template<int BN, bool OUT32>
__global__ __launch_bounds__(256) void gemm_split(
    const f16* __restrict__ Agh, const f16* __restrict__ Agl,
    const f16* __restrict__ BTh, const f16* __restrict__ BTl,
    const float* __restrict__ bias0, const float* __restrict__ bias1,
    void* __restrict__ C0v, void* __restrict__ C1v,
    int Nsplit, int ld0, int ld1, int K, float outscale)
{
    constexpr int WN = BN / 64;
    constexpr int WM = 4 / WN;
    constexpr int WI = 128 / (WM * 16);
    constexpr int LDK = 40;
    constexpr int NB = (BN * 4) / 256;

    __shared__ f16 Ah[128 * LDK], Al[128 * LDK];
    __shared__ f16 Bh[BN * LDK],  Bl[BN * LDK];

    const int tid = threadIdx.x;
    const int l = tid & 63, w = tid >> 6;
    const int l15 = l & 15, lq = l >> 4;
    const int wr = w / WN, wc = w % WN;

    // XCD swizzle: contiguous chunk of tiles per XCD
    const int nwgx = gridDim.x;
    const int orig = blockIdx.y * nwgx + blockIdx.x;
    const int cpx = (nwgx * gridDim.y) >> 3;
    const int sw = (orig & 7) * cpx + (orig >> 3);
    const int m0 = (sw / nwgx) << 7;
    const int n0 = (sw % nwgx) * BN;

    f32x4 acc[WI][4];
#pragma unroll
    for (int i = 0; i < WI; ++i)
#pragma unroll
        for (int j = 0; j < 4; ++j) acc[i][j] = (f32x4){0.f, 0.f, 0.f, 0.f};

    const int ar  = tid >> 2;
    const int auk = (tid & 3) << 3;
    const f16* Ahp = Agh + (size_t)(m0 + ar) * K + auk;
    const f16* Alp = Agl + (size_t)(m0 + ar) * K + auk;
    const int bnr = tid >> 2, buk = (tid & 3) << 3;
    const f16* Bhp = BTh + (size_t)(n0 + bnr) * K + buk;
    const f16* Blp = BTl + (size_t)(n0 + bnr) * K + buk;

    f16x8 a0h = *(const f16x8*)(Ahp);
    f16x8 a1h = *(const f16x8*)(Ahp + (size_t)64 * K);
    f16x8 a0l = *(const f16x8*)(Alp);
    f16x8 a1l = *(const f16x8*)(Alp + (size_t)64 * K);
    f16x8 bhv[NB], blv[NB];
#pragma unroll
    for (int it = 0; it < NB; ++it) {
        bhv[it] = *(const f16x8*)(Bhp + (size_t)(it * 64) * K);
        blv[it] = *(const f16x8*)(Blp + (size_t)(it * 64) * K);
    }

    for (int k0 = 0; k0 < K; k0 += 32) {
        __syncthreads();
        *(f16x8*)&Ah[ar * LDK + auk] = a0h;
        *(f16x8*)&Ah[(ar + 64) * LDK + auk] = a1h;
        *(f16x8*)&Al[ar * LDK + auk] = a0l;
        *(f16x8*)&Al[(ar + 64) * LDK + auk] = a1l;
#pragma unroll
        for (int it = 0; it < NB; ++it) {
            *(f16x8*)&Bh[(bnr + it * 64) * LDK + buk] = bhv[it];
            *(f16x8*)&Bl[(bnr + it * 64) * LDK + buk] = blv[it];
        }
        __syncthreads();

        const int kn = k0 + 32;
        a0h = *(const f16x8*)(Ahp + kn);
        a1h = *(const f16x8*)(Ahp + (size_t)64 * K + kn);
        a0l = *(const f16x8*)(Alp + kn);
        a1l = *(const f16x8*)(Alp + (size_t)64 * K + kn);
#pragma unroll
        for (int it = 0; it < NB; ++it) {
            bhv[it] = *(const f16x8*)(Bhp + (size_t)(it * 64) * K + kn);
            blv[it] = *(const f16x8*)(Blp + (size_t)(it * 64) * K + kn);
        }

        f16x8 afh[WI], afl[WI];
#pragma unroll
        for (int i = 0; i < WI; ++i) {
            const int row = wr * (WI * 16) + i * 16 + l15;
            afh[i] = *(const f16x8*)&Ah[row * LDK + lq * 8];
            afl[i] = *(const f16x8*)&Al[row * LDK + lq * 8];
        }
#pragma unroll
        for (int j = 0; j < 4; ++j) {
            const int bn = wc * 64 + j * 16 + l15;
            const f16x8 bfh = *(const f16x8*)&Bh[bn * LDK + lq * 8];
            const f16x8 bfl = *(const f16x8*)&Bl[bn * LDK + lq * 8];
#pragma unroll
            for (int i = 0; i < WI; ++i)
                acc[i][j] = __builtin_amdgcn_mfma_f32_16x16x32_f16(afh[i], bfh, acc[i][j], 0, 0, 0);
#pragma unroll
            for (int i = 0; i < WI; ++i)
                acc[i][j] = __builtin_amdgcn_mfma_f32_16x16x32_f16(afl[i], bfh, acc[i][j], 0, 0, 0);
#pragma unroll
            for (int i = 0; i < WI; ++i)
                acc[i][j] = __builtin_amdgcn_mfma_f32_16x16x32_f16(afh[i], bfl, acc[i][j], 0, 0, 0);
        }
    }

#pragma unroll
    for (int j = 0; j < 4; ++j) {
        const int ng = n0 + wc * 64 + j * 16 + l15;
        const bool first = ng < Nsplit;
        const float bvf = first ? bias0[ng] : bias1[ng - Nsplit];
        const int nc = first ? ng : ng - Nsplit;
        const int ldc = first ? ld0 : ld1;
#pragma unroll
        for (int i = 0; i < WI; ++i) {
            const int mg = m0 + wr * (WI * 16) + i * 16 + lq * 4;
#pragma unroll
            for (int r = 0; r < 4; ++r) {
                const float v = (acc[i][j][r] + bvf) * outscale;
                if (OUT32)
                    ((float*)(first ? C0v : C1v))[(size_t)(mg + r) * ldc + nc] = v;
                else
                    ((f16*)(first ? C0v : C1v))[(size_t)(mg + r) * ldc + nc] = (f16)v;
            }
        }
    }
}

#define SHUF8(x, y) __builtin_shufflevector(x, y, 0, 1, 2, 3, 4, 5, 6, 7)

// ---------------------------------------------------------------------------
// fp16-MFMA flash attention v4: 4 waves x 32 q-rows (QBLK=128), KV tile 64,
// double-buffered K/V via global_load_lds + counted vmcnt + raw barriers,
// tr16 V and tr16 P, per-db-pipelined PV with counted lgkmcnt.
// NEW: scores arrive in log2 units (log2e folded into Q-GEMM outscale) ->
// exp2-direct softmax; group-max defer (one running max per 4-row group,
// threshold 11.5 log2-units ~= 8 e-units) -> shuffle reductions cut 4x.
// ---------------------------------------------------------------------------
__global__ __launch_bounds__(256, 2) void flash_attn_mfma(
    const f16* __restrict__ Q, const f16* __restrict__ Kp,
    const f16* __restrict__ Vp, f16* __restrict__ AOh, f16* __restrict__ AOl)
{
    __shared__ f16 KsA[2][64 * 128];   // 32 KB
    __shared__ f16 VtA[2][64 * 128];   // 32 KB (tr16 subtiled)
    __shared__ f16 Pt[4][2048];        // 16 KB per-wave transposed P

    const int tid = threadIdx.x;
    const int w = tid >> 6, l = tid & 63;
    const int l15 = l & 15, lq = l >> 4;
    const int b = blockIdx.z, h = blockIdx.y, g = h >> 2;
    const int q0 = blockIdx.x << 7;    // 128 q-rows per block

    const f16* Qb = Q + (size_t)(b * SEQ + q0) * D_MODEL + h * HD;
    const f16* Kb = Kp + (size_t)b * SEQ * GHD + g * HD;
    const f16* Vb = Vp + (size_t)b * SEQ * GHD + g * HD;

    // Q fragments: wave owns rows [w*32, w*32+32) as 2 groups of 16
    f16x8 aq[2][4];
#pragma unroll
    for (int rg = 0; rg < 2; ++rg) {
        const f16* qrow = Qb + (size_t)(w * 32 + rg * 16 + l15) * D_MODEL;
#pragma unroll
        for (int c = 0; c < 4; ++c)
            aq[rg][c] = *(const f16x8*)(qrow + c * 32 + lq * 8);
    }

    // staging addresses (per-lane-permuted global source, linear LDS dest)
    lf16* Ks3 = (lf16*)&KsA[0][0];
    lf16* Vt3 = (lf16*)&VtA[0][0];
    const f16* ksrc[4]; lf16* kdst[4];
    const f16* vsrc[4]; lf16* vdst[4];
#pragma unroll
    for (int i = 0; i < 4; ++i) {
        const int s = tid + (i << 8);
        {
            const int row = s >> 4, ul = s & 15;
            ksrc[i] = Kb + (size_t)row * GHD + ((ul ^ (row & 7)) << 3);
            kdst[i] = Ks3 + s * 8;
        }
        {
            const int dbit = s & 1, kvlo = (s >> 1) & 3, vlq = (s >> 3) & 3;
            const int jh = (s >> 5) & 1, kc = (s >> 6) & 1, dsub = s >> 7;
            const int kv = (kc << 5) | (vlq << 3) | (jh << 2) | kvlo;
            vsrc[i] = Vb + (size_t)kv * GHD + ((dsub << 4) | (dbit << 3));
            vdst[i] = Vt3 + s * 8;
        }
    }
    const unsigned vta0 = (unsigned)(size_t)(Vt3 + l * 4);
    const unsigned vta1 = vta0 + 16384;
    f16* PtW = &Pt[w][0];
    const unsigned pta = (unsigned)(size_t)((lf16*)PtW + l * 4);
    // P-write lane-constant part (f16 units)
    const int pbl = ((l15 >> 2) & 1) * 256 + (l15 >> 3) * 64 + (l15 & 3) * 16 + lq * 4;

    f32x4 acc_o[2][8];
#pragma unroll
    for (int rg = 0; rg < 2; ++rg)
#pragma unroll
        for (int i = 0; i < 8; ++i) acc_o[rg][i] = (f32x4){0.f, 0.f, 0.f, 0.f};
    float m_rg[2] = {-1e30f, -1e30f};     // one running max per 4-row group
    float l_r[2][4];
#pragma unroll
    for (int rg = 0; rg < 2; ++rg)
#pragma unroll
        for (int r = 0; r < 4; ++r) l_r[rg][r] = 0.f;

    auto issue_tile = [&](int buf, int tile) {
        const size_t koff = (size_t)tile * 64 * GHD;
        const int KO = buf << 13;
#pragma unroll
        for (int i = 0; i < 4; ++i)
            __builtin_amdgcn_global_load_lds((gvoid*)(ksrc[i] + koff),
                                             (lvoid*)(kdst[i] + KO), 16, 0, 0);
#pragma unroll
        for (int i = 0; i < 4; ++i)
            __builtin_amdgcn_global_load_lds((gvoid*)(vsrc[i] + koff),
                                             (lvoid*)(vdst[i] + KO), 16, 0, 0);
    };

    auto compute_tile = [&](const f16* KsB, unsigned vtaB) {
        // ---- QK^T: S[32][64] per wave; each K-frag feeds both row-groups
        f32x4 sa[2][4];
        __builtin_amdgcn_s_setprio(1);
#pragma unroll
        for (int cb = 0; cb < 4; ++cb) {
            sa[0][cb] = (f32x4){0.f, 0.f, 0.f, 0.f};
            sa[1][cb] = (f32x4){0.f, 0.f, 0.f, 0.f};
#pragma unroll
            for (int c = 0; c < 4; ++c) {
                const int rk = cb * 16 + l15;
                const f16x8 bk = *(const f16x8*)&KsB[rk * 128 + (((c * 4 + lq) ^ (rk & 7)) << 3)];
                sa[0][cb] = __builtin_amdgcn_mfma_f32_16x16x32_f16(aq[0][c], bk, sa[0][cb], 0, 0, 0);
                sa[1][cb] = __builtin_amdgcn_mfma_f32_16x16x32_f16(aq[1][c], bk, sa[1][cb], 0, 0, 0);
            }
        }
        __builtin_amdgcn_s_setprio(0);

        // ---- softmax: group-max defer + exp2-direct; P stored transposed
#pragma unroll
        for (int rg = 0; rg < 2; ++rg) {
            float gm = sa[rg][0][0];
#pragma unroll
            for (int cb = 0; cb < 4; ++cb)
#pragma unroll
                for (int reg = 0; reg < 4; ++reg)
                    gm = fmaxf(gm, sa[rg][cb][reg]);
            gm = fmaxf(gm, __shfl_xor(gm, 1));
            gm = fmaxf(gm, __shfl_xor(gm, 2));
            gm = fmaxf(gm, __shfl_xor(gm, 4));
            gm = fmaxf(gm, __shfl_xor(gm, 8));
            if (gm > m_rg[rg] + 11.5f) {
                const float alpha = __builtin_amdgcn_exp2f(m_rg[rg] - gm);
                m_rg[rg] = gm;
#pragma unroll
                for (int reg = 0; reg < 4; ++reg) l_r[rg][reg] *= alpha;
#pragma unroll
                for (int db = 0; db < 8; ++db) acc_o[rg][db] *= alpha;
            }
#pragma unroll
            for (int cb = 0; cb < 4; ++cb) {
                f16x4 w4;
#pragma unroll
                for (int reg = 0; reg < 4; ++reg) {
                    const float p = __builtin_amdgcn_exp2f(sa[rg][cb][reg] - m_rg[rg]);
                    l_r[rg][reg] += p;
                    w4[reg] = (f16)p;
                }
                *(f16x4*)&PtW[rg * 1024 + (cb >> 1) * 512 + (cb & 1) * 128 + pbl] = w4;
            }
        }

        // ---- PV: per-db pipelined, counted lgkmcnt
        asm volatile("" ::: "memory");   // pin P-writes before the tr16 reads
        f16x8 pa[2][2];
#pragma unroll
        for (int rg = 0; rg < 2; ++rg)
#pragma unroll
            for (int kc = 0; kc < 2; ++kc) {
                f16x4 p0, p1;
                if (rg == 0 && kc == 0) { p0 = tr16<0>(pta);    p1 = tr16<512>(pta); }
                if (rg == 0 && kc == 1) { p0 = tr16<1024>(pta); p1 = tr16<1536>(pta); }
                if (rg == 1 && kc == 0) { p0 = tr16<2048>(pta); p1 = tr16<2560>(pta); }
                if (rg == 1 && kc == 1) { p0 = tr16<3072>(pta); p1 = tr16<3584>(pta); }
                pa[rg][kc] = SHUF8(p0, p1);
            }

        f16x8 v0k0, v0k1;
        {   // db = 0 V-frags
            f16x4 a0 = tr16<0>(vtaB),    b0 = tr16<512>(vtaB);
            f16x4 a1 = tr16<1024>(vtaB), b1 = tr16<1536>(vtaB);
            WAIT_LGKM(4);                // pa done (in-order DS); db0 V in flight
            v0k0 = SHUF8(a0, b0); v0k1 = SHUF8(a1, b1);
        }
#pragma unroll
        for (int db = 0; db < 8; ++db) {
            f16x8 n0, n1;
            if (db < 7) {
                f16x4 a0, b0, a1, b1;
                switch (db) {
                case 0: a0=tr16<2048>(vtaB);  b0=tr16<2560>(vtaB);  a1=tr16<3072>(vtaB);  b1=tr16<3584>(vtaB);  break;
                case 1: a0=tr16<4096>(vtaB);  b0=tr16<4608>(vtaB);  a1=tr16<5120>(vtaB);  b1=tr16<5632>(vtaB);  break;
                case 2: a0=tr16<6144>(vtaB);  b0=tr16<6656>(vtaB);  a1=tr16<7168>(vtaB);  b1=tr16<7680>(vtaB);  break;
                case 3: a0=tr16<8192>(vtaB);  b0=tr16<8704>(vtaB);  a1=tr16<9216>(vtaB);  b1=tr16<9728>(vtaB);  break;
                case 4: a0=tr16<10240>(vtaB); b0=tr16<10752>(vtaB); a1=tr16<11264>(vtaB); b1=tr16<11776>(vtaB); break;
                case 5: a0=tr16<12288>(vtaB); b0=tr16<12800>(vtaB); a1=tr16<13312>(vtaB); b1=tr16<13824>(vtaB); break;
                default:a0=tr16<14336>(vtaB); b0=tr16<14848>(vtaB); a1=tr16<15360>(vtaB); b1=tr16<15872>(vtaB); break;
                }
                WAIT_LGKM(4);            // V(db) done, V(db+1) in flight
                n0 = SHUF8(a0, b0); n1 = SHUF8(a1, b1);
            } else {
                WAIT_LGKM(0);
            }
            __builtin_amdgcn_s_setprio(1);
            acc_o[0][db] = __builtin_amdgcn_mfma_f32_16x16x32_f16(pa[0][0], v0k0, acc_o[0][db], 0, 0, 0);
            acc_o[1][db] = __builtin_amdgcn_mfma_f32_16x16x32_f16(pa[1][0], v0k0, acc_o[1][db], 0, 0, 0);
            acc_o[0][db] = __builtin_amdgcn_mfma_f32_16x16x32_f16(pa[0][1], v0k1, acc_o[0][db], 0, 0, 0);
            acc_o[1][db] = __builtin_amdgcn_mfma_f32_16x16x32_f16(pa[1][1], v0k1, acc_o[1][db], 0, 0, 0);
            __builtin_amdgcn_s_setprio(0);
            if (db < 7) { v0k0 = n0; v0k1 = n1; }
        }
    };

    // ---- pipelined main loop: 32 KV tiles, unrolled by 2 (static buffers)
    issue_tile(0, 0);
#pragma unroll 1
    for (int t2 = 0; t2 < 16; ++t2) {
        const int kt0 = t2 << 1;
        issue_tile(1, kt0 + 1);
        WAIT_VM8();
        BAR();
        compute_tile(&KsA[0][0], vta0);
        BAR();
        if (t2 < 15) {
            issue_tile(0, kt0 + 2);
            WAIT_VM8();
        } else {
            WAIT_VM0();
        }
        BAR();
        compute_tile(&KsA[1][0], vta1);
        BAR();
    }

    // ---- epilogue: reduce l across the 16-lane row group, normalize, store
    const size_t obase = (size_t)(b * SEQ + q0 + w * 32) * D_MODEL + h * HD;
#pragma unroll
    for (int rg = 0; rg < 2; ++rg) {
        float inv_l[4];
#pragma unroll
        for (int reg = 0; reg < 4; ++reg) {
            float s = l_r[rg][reg];
            s += __shfl_xor(s, 1);
            s += __shfl_xor(s, 2);
            s += __shfl_xor(s, 4);
            s += __shfl_xor(s, 8);
            inv_l[reg] = 1.f / s;
        }
#pragma unroll
        for (int db = 0; db < 8; ++db) {
#pragma unroll
            for (int reg = 0; reg < 4; ++reg) {
                const size_t off = obase + (size_t)(rg * 16 + lq * 4 + reg) * D_MODEL + db * 16 + l15;
                const float v = acc_o[rg][db][reg] * inv_l[reg];
                const f16 hh = (f16)v;
                AOh[off] = hh;
                AOl[off] = (f16)(v - (float)hh);
            }
        }
    }
}

extern "C" void kernel_launch(void* const* d_in, const int* in_sizes, int n_in,
                              void* d_out, int out_size, void* d_ws, size_t ws_size,
                              hipStream_t stream)
{
    const float* x  = (const float*)d_in[0];
    const float* Wq = (const float*)d_in[1];
    const float* bq = (const float*)d_in[2];
    const float* Wk = (const float*)d_in[3];
    const float* bk = (const float*)d_in[4];
    const float* Wv = (const float*)d_in[5];
    const float* bv = (const float*)d_in[6];
    const float* Wo = (const float*)d_in[7];
    const float* bo = (const float*)d_in[8];
    float* out = (float*)d_out;

    // workspace (f16 units), total 41,943,040 f16 = 83.9 MB.
    f16* base   = (f16*)d_ws;
    f16* xh     = base;                 // 8388608
    f16* xl     = base + 8388608;       // 8388608
    f16* WkvT_h = base + 16777216;      // 2097152
    f16* WkvT_l = base + 18874368;      // 2097152
    f16* WqoT_h = base + 20971520;      // 4194304
    f16* WqoT_l = base + 25165824;      // 4194304
    f16* Qp     = base + 29360128;      // 8388608
    f16* Kp     = base + 37748736;      // 2097152
    f16* Vp     = base + 39845888;      // 2097152 -> end 41943040
    f16* AOh    = xh;
    f16* AOl    = xl;

    const dim3 blk(256);
    // 1/sqrt(128) * log2(e): scores arrive in log2 units for exp2-direct softmax
    const float qscale = 0.08838834764831845f * 1.4426950408889634f;

    split_f32<<<dim3(M_TOT * D_MODEL / 8 / 256), blk, 0, stream>>>(x, xh, xl);
    transpose_split<<<dim3(64, 64), blk, 0, stream>>>(Wq, WqoT_h, WqoT_l, 2048, 2048, 0);
    transpose_split<<<dim3(16, 64), blk, 0, stream>>>(Wk, WkvT_h, WkvT_l, 2048, 512, 0);
    transpose_split<<<dim3(16, 64), blk, 0, stream>>>(Wv, WkvT_h, WkvT_l, 2048, 512, 512);

    gemm_split<128, false><<<dim3(16, 32), blk, 0, stream>>>(
        xh, xl, WqoT_h, WqoT_l, bq, bq, Qp, Qp, 2048, 2048, 2048, 2048, qscale);
    gemm_split<64, false><<<dim3(16, 32), blk, 0, stream>>>(
        xh, xl, WkvT_h, WkvT_l, bk, bv, Kp, Vp, 512, 512, 512, 2048, 1.0f);

    transpose_split<<<dim3(64, 64), blk, 0, stream>>>(Wo, WqoT_h, WqoT_l, 2048, 2048, 0);

    flash_attn_mfma<<<dim3(SEQ / 128, NQH, B_SZ), blk, 0, stream>>>(Qp, Kp, Vp, AOh, AOl);

    gemm_split<128, true><<<dim3(16, 32), blk, 0, stream>>>(
        AOh, AOl, WqoT_h, WqoT_l, bo, bo, out, out, 2048, 2048, 2048, 2048, 1.0f);
}

// Round 8
// 349.073 us; speedup vs baseline: 10.0959x; 1.1695x over previous
//
#include <hip/hip_runtime.h>

#define D_MODEL 2048
#define GHD 512        // NUM_KV_GROUPS * HEAD_DIM
#define HD 128
#define NQH 16
#define B_SZ 2
#define SEQ 2048
#define M_TOT (B_SZ * SEQ)   // 4096

typedef _Float16 f16;
typedef _Float16 f16x4 __attribute__((ext_vector_type(4)));
typedef _Float16 f16x8 __attribute__((ext_vector_type(8)));
typedef float f32x4 __attribute__((ext_vector_type(4)));

typedef const __attribute__((address_space(1))) void gvoid;
typedef __attribute__((address_space(3))) void lvoid;
typedef __attribute__((address_space(3))) f16 lf16;

// raw barrier (no vmcnt(0) drain) with compiler fences
#define BAR() do { asm volatile("" ::: "memory"); \
                   __builtin_amdgcn_s_barrier();  \
                   asm volatile("" ::: "memory"); } while (0)
#define WAIT_VM8() asm volatile("s_waitcnt vmcnt(8)" ::: "memory")
#define WAIT_VM0() asm volatile("s_waitcnt vmcnt(0)" ::: "memory")
#define WAIT_LGKM(N) do { asm volatile("s_waitcnt lgkmcnt(" #N ")" ::: "memory"); \
                          __builtin_amdgcn_sched_barrier(0); } while (0)

// hardware transpose read: with per-lane addr = base + l*8B, lane l elem j
// reads f16 at base_f16[OFF/2 + (l>>4)*64 + j*16 + (l&15)]
template<int OFF>
__device__ __forceinline__ f16x4 tr16(unsigned a) {
    f16x4 d;
    asm volatile("ds_read_b64_tr_b16 %0, %1 offset:%2"
                 : "=v"(d) : "v"(a), "i"(OFF));
    return d;
}

// ---------------------------------------------------------------------------
// x (fp32) -> hi/lo f16 split, elementwise
// ---------------------------------------------------------------------------
__global__ __launch_bounds__(256) void split_f32(
    const float* __restrict__ X, f16* __restrict__ Xh, f16* __restrict__ Xl)
{
    const size_t i = ((size_t)blockIdx.x * 256 + threadIdx.x) * 8;
    const float4 v0 = *(const float4*)(X + i);
    const float4 v1 = *(const float4*)(X + i + 4);
    const float a[8] = {v0.x, v0.y, v0.z, v0.w, v1.x, v1.y, v1.z, v1.w};
    f16x8 h, lo;
#pragma unroll
    for (int e = 0; e < 8; ++e) {
        h[e] = (f16)a[e];
        lo[e] = (f16)(a[e] - (float)h[e]);
    }
    *(f16x8*)(Xh + i) = h;
    *(f16x8*)(Xl + i) = lo;
}

// ---------------------------------------------------------------------------
// Transpose + f16 cast: W[K][N] fp32 -> Th[(row_off+n)][K] f16 (hi only —
// 2-term split GEMM never consumes W_lo)
// ---------------------------------------------------------------------------
__global__ __launch_bounds__(256) void transpose_cast(
    const float* __restrict__ W, f16* __restrict__ Th,
    int K, int N, int row_off)
{
    __shared__ float Ls[32][33];
    const int t = threadIdx.x;
    const int n0 = blockIdx.x << 5, k0 = blockIdx.y << 5;
    {
        const int kr = t >> 3, nq = (t & 7) << 2;
        const float4 v = *(const float4*)&W[(size_t)(k0 + kr) * N + n0 + nq];
        Ls[kr][nq + 0] = v.x; Ls[kr][nq + 1] = v.y;
        Ls[kr][nq + 2] = v.z; Ls[kr][nq + 3] = v.w;
    }
    __syncthreads();
    const int nr = t >> 3, kq = (t & 7) << 2;
    f16x4 hv;
#pragma unroll
    for (int e = 0; e < 4; ++e) hv[e] = (f16)Ls[kq + e][nr];
    *(f16x4*)&Th[(size_t)(row_off + n0 + nr) * K + k0 + kq] = hv;
}

// ---------------------------------------------------------------------------
// 2-term split-precision MFMA GEMM: C = (Ah+Al) @ Bh^T + bias
// (== full-precision A x f16-quantized W; W-quant error ~1.5e-3 absmax,
//  within the 5.3e-3 budget). BM=128, BK=32, 256 threads (4 waves).
// XCD-aware block swizzle (T1); nwg always 512 here (divisible by 8).
// ---------------------------------------------------------------------------
template<int BN, bool OUT32>
__global__ __launch_bounds__(256) void gemm_split(
    const f16* __restrict__ Agh, const f16* __restrict__ Agl,
    const f16* __restrict__ BTh,
    const float* __restrict__ bias0, const float* __restrict__ bias1,
    void* __restrict__ C0v, void* __restrict__ C1v,
    int Nsplit, int ld0, int ld1, int K, float outscale)
{
    constexpr int WN = BN / 64;
    constexpr int WM = 4 / WN;
    constexpr int WI = 128 / (WM * 16);
    constexpr int LDK = 40;
    constexpr int NB = (BN * 4) / 256;

    __shared__ f16 Ah[128 * LDK], Al[128 * LDK];
    __shared__ f16 Bh[BN * LDK];

    const int tid = threadIdx.x;
    const int l = tid & 63, w = tid >> 6;
    const int l15 = l & 15, lq = l >> 4;
    const int wr = w / WN, wc = w % WN;

    // XCD swizzle: contiguous chunk of tiles per XCD
    const int nwgx = gridDim.x;
    const int orig = blockIdx.y * nwgx + blockIdx.x;
    const int cpx = (nwgx * gridDim.y) >> 3;
    const int sw = (orig & 7) * cpx + (orig >> 3);
    const int m0 = (sw / nwgx) << 7;
    const int n0 = (sw % nwgx) * BN;

    f32x4 acc[WI][4];
#pragma unroll
    for (int i = 0; i < WI; ++i)
#pragma unroll
        for (int j = 0; j < 4; ++j) acc[i][j] = (f32x4){0.f, 0.f, 0.f, 0.f};

    const int ar  = tid >> 2;
    const int auk = (tid & 3) << 3;
    const f16* Ahp = Agh + (size_t)(m0 + ar) * K + auk;
    const f16* Alp = Agl + (size_t)(m0 + ar) * K + auk;
    const int bnr = tid >> 2, buk = (tid & 3) << 3;
    const f16* Bhp = BTh + (size_t)(n0 + bnr) * K + buk;

    f16x8 a0h = *(const f16x8*)(Ahp);
    f16x8 a1h = *(const f16x8*)(Ahp + (size_t)64 * K);
    f16x8 a0l = *(const f16x8*)(Alp);
    f16x8 a1l = *(const f16x8*)(Alp + (size_t)64 * K);
    f16x8 bhv[NB];
#pragma unroll
    for (int it = 0; it < NB; ++it)
        bhv[it] = *(const f16x8*)(Bhp + (size_t)(it * 64) * K);

    for (int k0 = 0; k0 < K; k0 += 32) {
        __syncthreads();
        *(f16x8*)&Ah[ar * LDK + auk] = a0h;
        *(f16x8*)&Ah[(ar + 64) * LDK + auk] = a1h;
        *(f16x8*)&Al[ar * LDK + auk] = a0l;
        *(f16x8*)&Al[(ar + 64) * LDK + auk] = a1l;
#pragma unroll
        for (int it = 0; it < NB; ++it)
            *(f16x8*)&Bh[(bnr + it * 64) * LDK + buk] = bhv[it];
        __syncthreads();

        // prefetch next k0 (flies under MFMA; last-iter over-read stays in ws)
        const int kn = k0 + 32;
        a0h = *(const f16x8*)(Ahp + kn);
        a1h = *(const f16x8*)(Ahp + (size_t)64 * K + kn);
        a0l = *(const f16x8*)(Alp + kn);
        a1l = *(const f16x8*)(Alp + (size_t)64 * K + kn);
#pragma unroll
        for (int it = 0; it < NB; ++it)
            bhv[it] = *(const f16x8*)(Bhp + (size_t)(it * 64) * K + kn);

        f16x8 afh[WI], afl[WI];
#pragma unroll
        for (int i = 0; i < WI; ++i) {
            const int row = wr * (WI * 16) + i * 16 + l15;
            afh[i] = *(const f16x8*)&Ah[row * LDK + lq * 8];
            afl[i] = *(const f16x8*)&Al[row * LDK + lq * 8];
        }
#pragma unroll
        for (int j = 0; j < 4; ++j) {
            const int bn = wc * 64 + j * 16 + l15;
            const f16x8 bfh = *(const f16x8*)&Bh[bn * LDK + lq * 8];
#pragma unroll
            for (int i = 0; i < WI; ++i)
                acc[i][j] = __builtin_amdgcn_mfma_f32_16x16x32_f16(afh[i], bfh, acc[i][j], 0, 0, 0);
#pragma unroll
            for (int i = 0; i < WI; ++i)
                acc[i][j] = __builtin_amdgcn_mfma_f32_16x16x32_f16(afl[i], bfh, acc[i][j], 0, 0, 0);
        }
    }

#pragma unroll
    for (int j = 0; j < 4; ++j) {
        const int ng = n0 + wc * 64 + j * 16 + l15;
        const bool first = ng < Nsplit;
        const float bvf = first ? bias0[ng] : bias1[ng - Nsplit];
        const int nc = first ? ng : ng - Nsplit;
        const int ldc = first ? ld0 : ld1;
#pragma unroll
        for (int i = 0; i < WI; ++i) {
            const int mg = m0 + wr * (WI * 16) + i * 16 + lq * 4;
#pragma unroll
            for (int r = 0; r < 4; ++r) {
                const float v = (acc[i][j][r] + bvf) * outscale;
                if (OUT32)
                    ((float*)(first ? C0v : C1v))[(size_t)(mg + r) * ldc + nc] = v;
                else
                    ((f16*)(first ? C0v : C1v))[(size_t)(mg + r) * ldc + nc] = (f16)v;
            }
        }
    }
}

#define SHUF8(x, y) __builtin_shufflevector(x, y, 0, 1, 2, 3, 4, 5, 6, 7)

// ---------------------------------------------------------------------------
// fp16-MFMA flash attention v4 (unchanged from round 7): 4 waves x 32 q-rows,
// KV tile 64, double-buffered K/V via global_load_lds + counted vmcnt + raw
// barriers, tr16 V and tr16 P, per-db-pipelined PV with counted lgkmcnt,
// exp2-direct softmax with group-max defer, hi/lo f16 output.
// ---------------------------------------------------------------------------
__global__ __launch_bounds__(256, 2) void flash_attn_mfma(
    const f16* __restrict__ Q, const f16* __restrict__ Kp,
    const f16* __restrict__ Vp, f16* __restrict__ AOh, f16* __restrict__ AOl)
{
    __shared__ f16 KsA[2][64 * 128];   // 32 KB
    __shared__ f16 VtA[2][64 * 128];   // 32 KB (tr16 subtiled)
    __shared__ f16 Pt[4][2048];        // 16 KB per-wave transposed P

    const int tid = threadIdx.x;
    const int w = tid >> 6, l = tid & 63;
    const int l15 = l & 15, lq = l >> 4;
    const int b = blockIdx.z, h = blockIdx.y, g = h >> 2;
    const int q0 = blockIdx.x << 7;    // 128 q-rows per block

    const f16* Qb = Q + (size_t)(b * SEQ + q0) * D_MODEL + h * HD;
    const f16* Kb = Kp + (size_t)b * SEQ * GHD + g * HD;
    const f16* Vb = Vp + (size_t)b * SEQ * GHD + g * HD;

    // Q fragments: wave owns rows [w*32, w*32+32) as 2 groups of 16
    f16x8 aq[2][4];
#pragma unroll
    for (int rg = 0; rg < 2; ++rg) {
        const f16* qrow = Qb + (size_t)(w * 32 + rg * 16 + l15) * D_MODEL;
#pragma unroll
        for (int c = 0; c < 4; ++c)
            aq[rg][c] = *(const f16x8*)(qrow + c * 32 + lq * 8);
    }

    // staging addresses (per-lane-permuted global source, linear LDS dest)
    lf16* Ks3 = (lf16*)&KsA[0][0];
    lf16* Vt3 = (lf16*)&VtA[0][0];
    const f16* ksrc[4]; lf16* kdst[4];
    const f16* vsrc[4]; lf16* vdst[4];
#pragma unroll
    for (int i = 0; i < 4; ++i) {
        const int s = tid + (i << 8);
        {
            const int row = s >> 4, ul = s & 15;
            ksrc[i] = Kb + (size_t)row * GHD + ((ul ^ (row & 7)) << 3);
            kdst[i] = Ks3 + s * 8;
        }
        {
            const int dbit = s & 1, kvlo = (s >> 1) & 3, vlq = (s >> 3) & 3;
            const int jh = (s >> 5) & 1, kc = (s >> 6) & 1, dsub = s >> 7;
            const int kv = (kc << 5) | (vlq << 3) | (jh << 2) | kvlo;
            vsrc[i] = Vb + (size_t)kv * GHD + ((dsub << 4) | (dbit << 3));
            vdst[i] = Vt3 + s * 8;
        }
    }
    const unsigned vta0 = (unsigned)(size_t)(Vt3 + l * 4);
    const unsigned vta1 = vta0 + 16384;
    f16* PtW = &Pt[w][0];
    const unsigned pta = (unsigned)(size_t)((lf16*)PtW + l * 4);
    const int pbl = ((l15 >> 2) & 1) * 256 + (l15 >> 3) * 64 + (l15 & 3) * 16 + lq * 4;

    f32x4 acc_o[2][8];
#pragma unroll
    for (int rg = 0; rg < 2; ++rg)
#pragma unroll
        for (int i = 0; i < 8; ++i) acc_o[rg][i] = (f32x4){0.f, 0.f, 0.f, 0.f};
    float m_rg[2] = {-1e30f, -1e30f};     // one running max per 4-row group
    float l_r[2][4];
#pragma unroll
    for (int rg = 0; rg < 2; ++rg)
#pragma unroll
        for (int r = 0; r < 4; ++r) l_r[rg][r] = 0.f;

    auto issue_tile = [&](int buf, int tile) {
        const size_t koff = (size_t)tile * 64 * GHD;
        const int KO = buf << 13;
#pragma unroll
        for (int i = 0; i < 4; ++i)
            __builtin_amdgcn_global_load_lds((gvoid*)(ksrc[i] + koff),
                                             (lvoid*)(kdst[i] + KO), 16, 0, 0);
#pragma unroll
        for (int i = 0; i < 4; ++i)
            __builtin_amdgcn_global_load_lds((gvoid*)(vsrc[i] + koff),
                                             (lvoid*)(vdst[i] + KO), 16, 0, 0);
    };

    auto compute_tile = [&](const f16* KsB, unsigned vtaB) {
        // ---- QK^T: S[32][64] per wave; each K-frag feeds both row-groups
        f32x4 sa[2][4];
        __builtin_amdgcn_s_setprio(1);
#pragma unroll
        for (int cb = 0; cb < 4; ++cb) {
            sa[0][cb] = (f32x4){0.f, 0.f, 0.f, 0.f};
            sa[1][cb] = (f32x4){0.f, 0.f, 0.f, 0.f};
#pragma unroll
            for (int c = 0; c < 4; ++c) {
                const int rk = cb * 16 + l15;
                const f16x8 bk = *(const f16x8*)&KsB[rk * 128 + (((c * 4 + lq) ^ (rk & 7)) << 3)];
                sa[0][cb] = __builtin_amdgcn_mfma_f32_16x16x32_f16(aq[0][c], bk, sa[0][cb], 0, 0, 0);
                sa[1][cb] = __builtin_amdgcn_mfma_f32_16x16x32_f16(aq[1][c], bk, sa[1][cb], 0, 0, 0);
            }
        }
        __builtin_amdgcn_s_setprio(0);

        // ---- softmax: group-max defer + exp2-direct; P stored transposed
#pragma unroll
        for (int rg = 0; rg < 2; ++rg) {
            float gm = sa[rg][0][0];
#pragma unroll
            for (int cb = 0; cb < 4; ++cb)
#pragma unroll
                for (int reg = 0; reg < 4; ++reg)
                    gm = fmaxf(gm, sa[rg][cb][reg]);
            gm = fmaxf(gm, __shfl_xor(gm, 1));
            gm = fmaxf(gm, __shfl_xor(gm, 2));
            gm = fmaxf(gm, __shfl_xor(gm, 4));
            gm = fmaxf(gm, __shfl_xor(gm, 8));
            if (gm > m_rg[rg] + 11.5f) {
                const float alpha = __builtin_amdgcn_exp2f(m_rg[rg] - gm);
                m_rg[rg] = gm;
#pragma unroll
                for (int reg = 0; reg < 4; ++reg) l_r[rg][reg] *= alpha;
#pragma unroll
                for (int db = 0; db < 8; ++db) acc_o[rg][db] *= alpha;
            }
#pragma unroll
            for (int cb = 0; cb < 4; ++cb) {
                f16x4 w4;
#pragma unroll
                for (int reg = 0; reg < 4; ++reg) {
                    const float p = __builtin_amdgcn_exp2f(sa[rg][cb][reg] - m_rg[rg]);
                    l_r[rg][reg] += p;
                    w4[reg] = (f16)p;
                }
                *(f16x4*)&PtW[rg * 1024 + (cb >> 1) * 512 + (cb & 1) * 128 + pbl] = w4;
            }
        }

        // ---- PV: per-db pipelined, counted lgkmcnt
        asm volatile("" ::: "memory");   // pin P-writes before the tr16 reads
        f16x8 pa[2][2];
#pragma unroll
        for (int rg = 0; rg < 2; ++rg)
#pragma unroll
            for (int kc = 0; kc < 2; ++kc) {
                f16x4 p0, p1;
                if (rg == 0 && kc == 0) { p0 = tr16<0>(pta);    p1 = tr16<512>(pta); }
                if (rg == 0 && kc == 1) { p0 = tr16<1024>(pta); p1 = tr16<1536>(pta); }
                if (rg == 1 && kc == 0) { p0 = tr16<2048>(pta); p1 = tr16<2560>(pta); }
                if (rg == 1 && kc == 1) { p0 = tr16<3072>(pta); p1 = tr16<3584>(pta); }
                pa[rg][kc] = SHUF8(p0, p1);
            }

        f16x8 v0k0, v0k1;
        {   // db = 0 V-frags
            f16x4 a0 = tr16<0>(vtaB),    b0 = tr16<512>(vtaB);
            f16x4 a1 = tr16<1024>(vtaB), b1 = tr16<1536>(vtaB);
            WAIT_LGKM(4);                // pa done (in-order DS); db0 V in flight
            v0k0 = SHUF8(a0, b0); v0k1 = SHUF8(a1, b1);
        }
#pragma unroll
        for (int db = 0; db < 8; ++db) {
            f16x8 n0, n1;
            if (db < 7) {
                f16x4 a0, b0, a1, b1;
                switch (db) {
                case 0: a0=tr16<2048>(vtaB);  b0=tr16<2560>(vtaB);  a1=tr16<3072>(vtaB);  b1=tr16<3584>(vtaB);  break;
                case 1: a0=tr16<4096>(vtaB);  b0=tr16<4608>(vtaB);  a1=tr16<5120>(vtaB);  b1=tr16<5632>(vtaB);  break;
                case 2: a0=tr16<6144>(vtaB);  b0=tr16<6656>(vtaB);  a1=tr16<7168>(vtaB);  b1=tr16<7680>(vtaB);  break;
                case 3: a0=tr16<8192>(vtaB);  b0=tr16<8704>(vtaB);  a1=tr16<9216>(vtaB);  b1=tr16<9728>(vtaB);  break;
                case 4: a0=tr16<10240>(vtaB); b0=tr16<10752>(vtaB); a1=tr16<11264>(vtaB); b1=tr16<11776>(vtaB); break;
                case 5: a0=tr16<12288>(vtaB); b0=tr16<12800>(vtaB); a1=tr16<13312>(vtaB); b1=tr16<13824>(vtaB); break;
                default:a0=tr16<14336>(vtaB); b0=tr16<14848>(vtaB); a1=tr16<15360>(vtaB); b1=tr16<15872>(vtaB); break;
                }
                WAIT_LGKM(4);            // V(db) done, V(db+1) in flight
                n0 = SHUF8(a0, b0); n1 = SHUF8(a1, b1);
            } else {
                WAIT_LGKM(0);
            }
            __builtin_amdgcn_s_setprio(1);
            acc_o[0][db] = __builtin_amdgcn_mfma_f32_16x16x32_f16(pa[0][0], v0k0, acc_o[0][db], 0, 0, 0);
            acc_o[1][db] = __builtin_amdgcn_mfma_f32_16x16x32_f16(pa[1][0], v0k0, acc_o[1][db], 0, 0, 0);
            acc_o[0][db] = __builtin_amdgcn_mfma_f32_16x16x32_f16(pa[0][1], v0k1, acc_o[0][db], 0, 0, 0);
            acc_o[1][db] = __builtin_amdgcn_mfma_f32_16x16x32_f16(pa[1][1], v0k1, acc_o[1][db], 0, 0, 0);
            __builtin_amdgcn_s_setprio(0);
            if (db < 7) { v0k0 = n0; v0k1 = n1; }
        }
    };

    // ---- pipelined main loop: 32 KV tiles, unrolled by 2 (static buffers)
    issue_tile(0, 0);
#pragma unroll 1
    for (int t2 = 0; t2 < 16; ++t2) {
        const int kt0 = t2 << 1;
        issue_tile(1, kt0 + 1);
        WAIT_VM8();
        BAR();
        compute_tile(&KsA[0][0], vta0);
        BAR();
        if (t2 < 15) {
            issue_tile(0, kt0 + 2);
            WAIT_VM8();
        } else {
            WAIT_VM0();
        }
        BAR();
        compute_tile(&KsA[1][0], vta1);
        BAR();
    }

    // ---- epilogue: reduce l across the 16-lane row group, normalize, store
    const size_t obase = (size_t)(b * SEQ + q0 + w * 32) * D_MODEL + h * HD;
#pragma unroll
    for (int rg = 0; rg < 2; ++rg) {
        float inv_l[4];
#pragma unroll
        for (int reg = 0; reg < 4; ++reg) {
            float s = l_r[rg][reg];
            s += __shfl_xor(s, 1);
            s += __shfl_xor(s, 2);
            s += __shfl_xor(s, 4);
            s += __shfl_xor(s, 8);
            inv_l[reg] = 1.f / s;
        }
#pragma unroll
        for (int db = 0; db < 8; ++db) {
#pragma unroll
            for (int reg = 0; reg < 4; ++reg) {
                const size_t off = obase + (size_t)(rg * 16 + lq * 4 + reg) * D_MODEL + db * 16 + l15;
                const float v = acc_o[rg][db][reg] * inv_l[reg];
                const f16 hh = (f16)v;
                AOh[off] = hh;
                AOl[off] = (f16)(v - (float)hh);
            }
        }
    }
}

extern "C" void kernel_launch(void* const* d_in, const int* in_sizes, int n_in,
                              void* d_out, int out_size, void* d_ws, size_t ws_size,
                              hipStream_t stream)
{
    const float* x  = (const float*)d_in[0];
    const float* Wq = (const float*)d_in[1];
    const float* bq = (const float*)d_in[2];
    const float* Wk = (const float*)d_in[3];
    const float* bk = (const float*)d_in[4];
    const float* Wv = (const float*)d_in[5];
    const float* bv = (const float*)d_in[6];
    const float* Wo = (const float*)d_in[7];
    const float* bo = (const float*)d_in[8];
    float* out = (float*)d_out;

    // workspace (f16 units), total 41,943,040 f16 = 83.9 MB (same footprint;
    // former W_lo slots are now unused slack that also absorbs prefetch
    // over-reads). AOh/AOl alias xh/xl (x dead after Q/KV GEMMs).
    f16* base  = (f16*)d_ws;
    f16* xh    = base;                 // 8388608
    f16* xl    = base + 8388608;       // 8388608
    f16* WkvT  = base + 16777216;      // 2097152 (K rows 0..511, V rows 512..1023)
    f16* WqoT  = base + 20971520;      // 4194304 (Wq, later Wo)
    f16* Qp    = base + 29360128;      // 8388608
    f16* Kp    = base + 37748736;      // 2097152
    f16* Vp    = base + 39845888;      // 2097152 -> end 41943040
    f16* AOh   = xh;
    f16* AOl   = xl;

    const dim3 blk(256);
    // 1/sqrt(128) * log2(e): scores arrive in log2 units for exp2-direct softmax
    const float qscale = 0.08838834764831845f * 1.4426950408889634f;

    split_f32<<<dim3(M_TOT * D_MODEL / 8 / 256), blk, 0, stream>>>(x, xh, xl);
    transpose_cast<<<dim3(64, 64), blk, 0, stream>>>(Wq, WqoT, 2048, 2048, 0);
    transpose_cast<<<dim3(16, 64), blk, 0, stream>>>(Wk, WkvT, 2048, 512, 0);
    transpose_cast<<<dim3(16, 64), blk, 0, stream>>>(Wv, WkvT, 2048, 512, 512);

    gemm_split<128, false><<<dim3(16, 32), blk, 0, stream>>>(
        xh, xl, WqoT, bq, bq, Qp, Qp, 2048, 2048, 2048, 2048, qscale);
    gemm_split<64, false><<<dim3(16, 32), blk, 0, stream>>>(
        xh, xl, WkvT, bk, bv, Kp, Vp, 512, 512, 512, 2048, 1.0f);

    // Wo^T into the (now dead) Wq^T slot, before attention overwrites xh/xl
    transpose_cast<<<dim3(64, 64), blk, 0, stream>>>(Wo, WqoT, 2048, 2048, 0);

    flash_attn_mfma<<<dim3(SEQ / 128, NQH, B_SZ), blk, 0, stream>>>(Qp, Kp, Vp, AOh, AOl);

    gemm_split<128, true><<<dim3(16, 32), blk, 0, stream>>>(
        AOh, AOl, WqoT, bo, bo, out, out, 2048, 2048, 2048, 2048, 1.0f);
}